// Round 16
// baseline (1538.778 us; speedup 1.0000x reference)
//
#include <hip/hip_runtime.h>
#include <math.h>

#define NN 128
#define BLK 256

__device__ __forceinline__ float hsum4(float4 v) { return (v.x + v.y) + (v.z + v.w); }

__device__ __forceinline__ float bcast(float v, int lane) {
  return __int_as_float(__builtin_amdgcn_readlane(__float_as_int(v), lane));
}

__device__ __forceinline__ double waveRedD(double v) {
#pragma unroll
  for (int off = 32; off > 0; off >>= 1) v += __shfl_down(v, off, 64);
  return v;
}
__device__ __forceinline__ float waveRedF(float v) {
#pragma unroll
  for (int off = 32; off > 0; off >>= 1) v += __shfl_down(v, off, 64);
  return v;
}
__device__ __forceinline__ float waveAllRedF(float v) {
#pragma unroll
  for (int off = 32; off > 0; off >>= 1) v += __shfl_xor(v, off, 64);
  return v;
}
__device__ __forceinline__ float getc(float4 a, int c) {
  return (c == 0) ? a.x : (c == 1) ? a.y : (c == 2) ? a.z : a.w;
}
__device__ __forceinline__ double blockReduceSum(double v, double* red, int tid) {
  v = waveRedD(v);
  __syncthreads();
  if ((tid & 63) == 0) red[tid >> 6] = v;
  __syncthreads();
  return (red[0] + red[1]) + (red[2] + red[3]);
}
__device__ __forceinline__ float startvec(int i, int k) {
  unsigned h = (unsigned)(i * 1664525 + k * 1013904223 + 12345);
  h ^= h >> 13; h *= 2654435761u; h ^= h >> 16;
  return ((float)(h & 0xFFFFFFu) * (1.0f / 16777216.0f)) - 0.5f;
}

extern "C" __global__ void __launch_bounds__(BLK, 4)
holo_kernel(const float* __restrict__ A, const float* __restrict__ F,
            const float* __restrict__ swg, const float* __restrict__ curv,
            const float* __restrict__ W1, const float* __restrict__ Bb1,
            const float* __restrict__ W2, const float* __restrict__ Bb2,
            const float* __restrict__ OW1, const float* __restrict__ OB1,
            const float* __restrict__ OW2, const float* __restrict__ OB2,
            float* __restrict__ out, int B)
{
  __shared__ __align__(16) float wsA[NN * 17];   // pre: scratch arrays; post: byv
  __shared__ __align__(16) float wsB[NN * 17];   // Householder: fscr+corner; invit: sA; MLP
  __shared__ unsigned swb[16 * 5];
  __shared__ double dd[NN], ee[NN], ee2[NN];
  __shared__ float  tvecf[NN];
  __shared__ double red[4], sc[8];
  __shared__ float  redupf[2], redutf[2], redsigf[2];
  __shared__ double lam[20], blo[17], bhi[17];
  __shared__ int    bcnt[119];
  __shared__ double ssv[16], dred[16];
  __shared__ float  msv[64], pool[16], zrow[16];

  double* dscr  = (double*)wsA;        // [256] (init only)
  float* svec   = wsA + 512;
  float* invdeg = wsA + 640;
  float* gvv    = wsA + 768;
  float* cw     = wsA + 896;
  float* ubuf   = wsA + 1024;
  float* pbuf   = wsA + 1152;
  float* colk   = wsA + 1280;
  float* byv    = wsA;                 // [128*17] after Householder
  float* fscr   = wsB;                 // [256] during Householder
  float* cornr  = wsB + 256;           // [32*33] corner transfer (after block loop)
  float* sA     = wsB;                 // [128*17] invit LU store
  float* comb   = wsB;                 // [128] MLP
  float* hbuf   = wsB + 128;

  const int  tid  = threadIdx.x;
  const int  r    = tid & 127;   // row owned
  const int  h    = tid >> 7;    // column half (cols 64h..64h+63)
  const int  lane = tid & 63;
  const int  widm = tid >> 6;
  const long b    = blockIdx.x;
  const float* Ab = A + b * (long)(NN * NN);
  const float* Fb = F + b * (long)(NN * 64);

  // ---------------- load A: each thread owns half a row in registers ----------------
  float4 areg[16];
  {
    const float4* Arow = reinterpret_cast<const float4*>(Ab + (long)r * NN) + 16 * h;
#pragma unroll
    for (int uu = 0; uu < 16; ++uu) areg[uu] = Arow[uu];
  }
  if (tid == 0) {
    const float a0 = swg[0], a1 = swg[1], a2 = swg[2];
    const float mx = fmaxf(a0, fmaxf(a1, a2));
    const float e0 = expf(a0 - mx), e1 = expf(a1 - mx), e2v = expf(a2 - mx);
    const float s = e0 + e1 + e2v;
    sc[0] = (double)(e0 / s); sc[1] = (double)(e1 / s); sc[2] = (double)(e2v / s);
  }
  // ---------------- degrees ----------------
  {
    float4 s4 = make_float4(0.f, 0.f, 0.f, 0.f);
#pragma unroll
    for (int uu = 0; uu < 16; ++uu) {
      s4.x += areg[uu].x; s4.y += areg[uu].y; s4.z += areg[uu].z; s4.w += areg[uu].w;
    }
    dscr[tid] = (double)hsum4(s4);
  }
  __syncthreads();
  if (tid < NN) {
    const double dg = dscr[tid] + dscr[tid + NN] + 1e-8;
    invdeg[tid] = (float)(1.0 / dg);
    svec[tid]   = (float)(1.0 / sqrt(dg));
  }
  __syncthreads();
  // g = R^T 1
  {
    const float4* iv4 = (const float4*)invdeg;
    float4 acc = make_float4(0.f, 0.f, 0.f, 0.f);
#pragma unroll
    for (int uu = 0; uu < 16; ++uu) {
      const float4 a = areg[uu], w = iv4[16 * h + uu];
      acc.x = fmaf(a.x, w.x, acc.x); acc.y = fmaf(a.y, w.y, acc.y);
      acc.z = fmaf(a.z, w.z, acc.z); acc.w = fmaf(a.w, w.w, acc.w);
    }
    fscr[tid] = hsum4(acc);
  }
  __syncthreads();
  if (tid < NN) {
    const float gv = fscr[tid] + fscr[tid + NN];
    gvv[tid] = gv;
    ubuf[tid] = gv * invdeg[tid];
  }
  __syncthreads();
  // hv = R^T g
  {
    const float4* ub4 = (const float4*)ubuf;
    float4 acc = make_float4(0.f, 0.f, 0.f, 0.f);
#pragma unroll
    for (int uu = 0; uu < 16; ++uu) {
      const float4 a = areg[uu], w = ub4[16 * h + uu];
      acc.x = fmaf(a.x, w.x, acc.x); acc.y = fmaf(a.y, w.y, acc.y);
      acc.z = fmaf(a.z, w.z, acc.z); acc.w = fmaf(a.w, w.w, acc.w);
    }
    fscr[tid] = hsum4(acc);
  }
  __syncthreads();
  if (tid < NN) {
    const float hv = fscr[tid] + fscr[tid + NN];
    cw[tid] = ((float)sc[0] + (float)sc[1] * gvv[tid] + (float)sc[2] * hv) * (1.0f / NN);
  }
  __syncthreads();
  // ms[d] = sum_n cw[n] F[n][d]
  {
    const int d = tid & 63, qt = tid >> 6;
    float acc = 0.0f;
    const float* fb = Fb + qt * 32 * 64;
    for (int n = 0; n < 32; ++n) acc = fmaf(cw[qt * 32 + n], fb[n * 64 + d], acc);
    fscr[tid] = acc;
  }
  __syncthreads();
  if (tid < 64) msv[tid] = (fscr[tid] + fscr[64 + tid]) + (fscr[128 + tid] + fscr[192 + tid]);

  // ---------------- L = I - D^-1/2 A D^-1/2 (registers) ----------------
  {
    const float sr = svec[r];
    const float4* sv4p = (const float4*)svec;
#pragma unroll
    for (int uu = 0; uu < 16; ++uu) {
      const float4 sv = sv4p[16 * h + uu];
      float4 a = areg[uu];
      a.x = -a.x * sr * sv.x; a.y = -a.y * sr * sv.y;
      a.z = -a.z * sr * sv.z; a.w = -a.w * sr * sv.w;
      areg[uu] = a;
    }
    if ((r >> 6) == h) {
      const int cl = r & 63, du = cl >> 2, dc = cl & 3;
#pragma unroll
      for (int uu = 0; uu < 16; ++uu) if (uu == du) {
        float4 a = areg[uu];
        a.x += (dc == 0) ? 1.f : 0.f; a.y += (dc == 1) ? 1.f : 0.f;
        a.z += (dc == 2) ? 1.f : 0.f; a.w += (dc == 3) ? 1.f : 0.f;
        areg[uu] = a;
      }
    }
  }
  // ---------------- prologue: column 0 extract + sigma + tvec init ----------------
  if (tid < NN) tvecf[tid] = 1.0f;
  if (h == 0) {
    const float v0 = areg[0].x;                // column 0
    colk[r] = v0;
    if (r == 0) dd[0] = (double)v0;
    const float s = waveRedF((r >= 2) ? v0 * v0 : 0.f);
    if (lane == 0) redsigf[widm] = s;
  }
  __syncthreads();

  // ---------------- Householder block phase: k = 0..94 (4 barriers/iter) ----------------
  for (int k = 0; k < 95; ++k) {
    const float sigma  = redsigf[0] + redsigf[1];
    const float alphaf = colk[k + 1];
    double betad; float tauf, sclf;
    if (sigma <= 0.f) { betad = (double)alphaf; tauf = 0.f; sclf = 0.f; }
    else {
      betad = -copysign(sqrt((double)alphaf * (double)alphaf + (double)sigma), (double)alphaf);
      const float betaf = (float)betad;
      tauf = (betaf - alphaf) / betaf;
      sclf = 1.0f / (alphaf - betaf);
    }
    if (tid == 0) ee[k] = betad;
    if (h == 0) ubuf[r] = (r <= k) ? 0.f : (r == k + 1) ? 1.f : colk[r] * sclf;
    __syncthreads();                                   // A
    // matvec partials (registers x LDS b128 broadcast u)
    {
      float4 acc = make_float4(0.f, 0.f, 0.f, 0.f);
      if (r >= k + 1 && 64 * h + 63 >= k + 1 && tauf != 0.f) {
        const float4* ub4 = (const float4*)ubuf;
#pragma unroll
        for (int uu = 0; uu < 16; ++uu) {
          if (64 * h + 4 * uu + 3 >= k + 1) {
            const float4 a = areg[uu], u4 = ub4[16 * h + uu];
            acc.x = fmaf(a.x, u4.x, acc.x); acc.y = fmaf(a.y, u4.y, acc.y);
            acc.z = fmaf(a.z, u4.z, acc.z); acc.w = fmaf(a.w, u4.w, acc.w);
          }
        }
      }
      fscr[tid] = hsum4(acc);
    }
    __syncthreads();                                   // B
    if (h == 0) {
      const float p = tauf * (fscr[r] + fscr[r + NN]);
      pbuf[r] = p;
      const float uv = ubuf[r];
      const float s1 = waveRedF(uv * p);
      const float s2 = waveRedF(uv * tvecf[r]);
      if (lane == 0) { redupf[widm] = s1; redutf[widm] = s2; }
    }
    __syncthreads();                                   // C
    // rank-2 update via readlane broadcasts (lane-distributed u/p copies)
    // Loads + q computed in UNIFORM flow and pinned so all 64 lanes hold
    // fresh values before the divergent guard (readlane reads any lane).
    {
      const float K   = 0.5f * tauf * (redupf[0] + redupf[1]);
      const float tut = tauf * (redutf[0] + redutf[1]);
      float u_w = ubuf[64 * h + lane];           // this wave's column-half slice
      float p_w = pbuf[64 * h + lane];
      asm volatile("" : "+v"(u_w), "+v"(p_w));   // pin: forbid sinking into branch
      float q_w = fmaf(-K, u_w, p_w);
      asm volatile("" : "+v"(q_w));
      if (r >= k + 1) {
        const float ur = ubuf[r];
        const float qr = fmaf(-K, ur, pbuf[r]);
        if (64 * h + 63 >= k + 1) {
#pragma unroll
          for (int uu = 0; uu < 16; ++uu) {
            if (64 * h + 4 * uu + 3 >= k + 1) {
              float4 a = areg[uu];
              const float u0 = bcast(u_w, 4 * uu + 0), q0 = bcast(q_w, 4 * uu + 0);
              const float u1 = bcast(u_w, 4 * uu + 1), q1 = bcast(q_w, 4 * uu + 1);
              const float u2 = bcast(u_w, 4 * uu + 2), q2 = bcast(q_w, 4 * uu + 2);
              const float u3 = bcast(u_w, 4 * uu + 3), q3 = bcast(q_w, 4 * uu + 3);
              a.x -= ur * q0 + qr * u0;
              a.y -= ur * q1 + qr * u1;
              a.z -= ur * q2 + qr * u2;
              a.w -= ur * q3 + qr * u3;
              areg[uu] = a;
            }
          }
        }
        if (h == 0) tvecf[r] -= tut * ubuf[r];
      }
      const int hstar = (k + 1) >> 6;                  // wave-uniform
      if (h == hstar) {
        float sigp = 0.0f;
        if (r >= k + 1) {
          const int cl = (k + 1) - 64 * hstar, du = cl >> 2, dc = cl & 3;
          float val = 0.f;
#pragma unroll
          for (int uu = 0; uu < 16; ++uu) if (uu == du) val = getc(areg[uu], dc);
          if (r == k + 1) dd[k + 1] = (double)val;
          else {
            colk[r] = val;
            if (r >= k + 3) sigp = val * val;
          }
        }
        const float s = waveRedF(sigp);
        if (lane == 0) redsigf[widm & 1] = s;
      }
    }
    __syncthreads();                                   // D
  }

  // ---------------- transfer trailing 32x32 (rows/cols 96..127) to LDS ----------------
  if (h == 1 && r >= 96) {                             // tids 224..255
    const int rl = r - 96;
#pragma unroll
    for (int uu = 8; uu < 16; ++uu) {
      const int j0 = (uu - 8) * 4;
      cornr[rl * 33 + j0 + 0] = areg[uu].x;
      cornr[rl * 33 + j0 + 1] = areg[uu].y;
      cornr[rl * 33 + j0 + 2] = areg[uu].z;
      cornr[rl * 33 + j0 + 3] = areg[uu].w;
    }
  }
  __syncthreads();

  // ---------------- wave-synchronous 32x32 corner: k = 95..125 (wave 0, no barriers) ----------------
  if (tid < 64) {
    const bool own = (lane < 32);                      // lane l owns row 96+l
    float arow[32];
#pragma unroll
    for (int j = 0; j < 32; ++j) arow[j] = own ? cornr[lane * 33 + j] : 0.f;
    float colval = own ? colk[96 + lane] : 0.f;        // column 95, rows 96..127
    float tv     = own ? tvecf[96 + lane] : 0.f;

    for (int k = 95; k <= 125; ++k) {
      const int kk = k - 95;
      const float sigp  = (lane >= kk + 1 && lane < 32) ? colval * colval : 0.f;
      const float sigma = waveAllRedF(sigp);
      const float alphaf = bcast(colval, kk);
      float betaf, tauf, sclf;
      if (sigma <= 0.f) { betaf = alphaf; tauf = 0.f; sclf = 0.f; }
      else {
        betaf = -copysignf(sqrtf(fmaf(alphaf, alphaf, sigma)), alphaf);
        tauf = (betaf - alphaf) / betaf;
        sclf = 1.0f / (alphaf - betaf);
      }
      if (lane == 0) ee[k] = (double)betaf;
      const bool live = own && (lane >= kk);
      const float u_me = !live ? 0.f : (lane == kk ? 1.f : colval * sclf);
      float y = 0.f;
#pragma unroll
      for (int j = 0; j < 32; ++j) y = fmaf(arow[j], bcast(u_me, j), y);
      const float p_me = live ? tauf * y : 0.f;
      const float up = waveAllRedF(u_me * p_me);
      const float ut = waveAllRedF(u_me * tv);
      const float K   = 0.5f * tauf * up;
      const float tut = tauf * ut;
      const float q_me = fmaf(-K, u_me, p_me);
      tv -= tut * u_me;
      float ncol = 0.f;
#pragma unroll
      for (int j = 0; j < 32; ++j) {
        const float uj = bcast(u_me, j);
        const float qj = bcast(q_me, j);
        arow[j] -= u_me * qj + q_me * uj;
        if (j == kk) ncol = arow[j];
      }
      if (lane == 0) dd[k + 1] = (double)bcast(ncol, kk);
      colval = (lane > kk && lane < 32) ? ncol : 0.f;
    }
    const float e126 = bcast(colval, 31);
    const float d127 = bcast(arow[31], 31);
    if (lane == 0) { ee[NN - 2] = (double)e126; dd[NN - 1] = (double)d127; }
    if (own) tvecf[96 + lane] = tv;
  }
  __syncthreads();

  // ---------------- bisection (multisection x7, 11 rounds) ----------------
  if (tid < NN - 1) ee2[tid] = ee[tid] * ee[tid];
  if (tid == 0) {
    double lo = 1e300, hi = -1e300;
    for (int i = 0; i < NN; ++i) {
      const double rr = ((i > 0) ? fabs(ee[i - 1]) : 0.0) + ((i < NN - 1) ? fabs(ee[i]) : 0.0);
      lo = fmin(lo, dd[i] - rr);
      hi = fmax(hi, dd[i] + rr);
    }
    sc[4] = lo - 1e-6; sc[5] = hi + 1e-6;
  }
  __syncthreads();
  if (tid < 17) { blo[tid] = sc[4]; bhi[tid] = sc[5]; }
  __syncthreads();
  for (int round = 0; round < 11; ++round) {
    if (tid < 119) {
      const int ke = tid / 7, j = tid % 7;
      const double lo = blo[ke], hi = bhi[ke];
      const double x = lo + (hi - lo) * ((double)(j + 1) * 0.125);
      int cnt = 0;
      double pm = 1.0, p = dd[0] - x;
      if (p < 0.0) cnt++;
      for (int i = 1; i < NN; ++i) {
        const double pn = (dd[i] - x) * p - ee2[i - 1] * pm;
        pm = p; p = pn;
        if ((p < 0.0) != (pm < 0.0)) cnt++;
        const double ap = fabs(p);
        if (ap > 1e100)                   { p *= 1e-100; pm *= 1e-100; }
        else if (ap < 1e-100 && ap > 0.0) { p *= 1e100;  pm *= 1e100; }
      }
      bcnt[tid] = cnt;
    }
    __syncthreads();
    if (tid < 17) {
      const double lo = blo[tid], hi = bhi[tid];
      const double w8 = (hi - lo) * 0.125;
      double nlo = lo, nhi = hi;
      for (int jj = 0; jj < 7; ++jj) {
        const double x = lo + w8 * (double)(jj + 1);
        if (bcnt[tid * 7 + jj] <= tid) nlo = x; else { nhi = x; break; }
      }
      blo[tid] = nlo; bhi[tid] = nhi;
    }
    __syncthreads();
  }
  if (tid < 17) lam[tid] = 0.5 * (blo[tid] + bhi[tid]);
  __syncthreads();

  // ---------------- inverse iteration on T (lanes 0..15), compressed LU ----------------
  if (tid < 16) {
    const double lk = lam[tid + 1];
    for (int it = 0; it < 2; ++it) {
      float beta = (float)(dd[0] - lk);
      float gam  = (float)ee[0];
      float rr   = (it == 0) ? startvec(0, tid) : byv[0 * 17 + tid];
      unsigned bw = 0;
      for (int i = 1; i < NN; ++i) {
        const int j = i - 1;
        const float ai = (float)ee[i - 1];
        const float bi = (float)(dd[i] - lk);
        const float ci = (i < NN - 1) ? (float)ee[i] : 0.0f;
        const float ri = (it == 0) ? startvec(i, tid) : byv[i * 17 + tid];
        if (fabsf(beta) >= fabsf(ai)) {
          float piv = (beta == 0.0f) ? 1e-25f : beta;
          const float mm = ai / piv;
          sA [j * 17 + tid] = piv;
          byv[j * 17 + tid] = rr;
          beta = bi - mm * gam;  gam = ci;  rr = ri - mm * rr;
        } else {
          const float mm = beta / ai;
          sA [j * 17 + tid] = mm;
          byv[j * 17 + tid] = ri;
          beta = gam - mm * bi;  gam = -mm * ci;  rr = rr - mm * ri;
          bw |= 1u << (j & 31);
        }
        if ((j & 31) == 31) { swb[tid * 5 + (j >> 5)] = bw; bw = 0; }
      }
      if (beta == 0.0f) beta = 1e-25f;
      sA [127 * 17 + tid] = beta;
      byv[127 * 17 + tid] = rr;
      swb[tid * 5 + 3] = bw;
      float y1 = 0.0f, y2 = 0.0f;
      for (int j = NN - 1; j >= 0; --j) {
        const bool sj = (swb[tid * 5 + (j >> 5)] >> (j & 31)) & 1;
        const bool sjm1 = (j > 0) ? ((swb[tid * 5 + ((j - 1) >> 5)] >> ((j - 1) & 31)) & 1) : false;
        float u0, u1, u2;
        if (sj) {
          u0 = (float)ee[j];
          u1 = (float)(dd[j + 1] - lk);
          u2 = (j < NN - 2) ? (float)ee[j + 1] : 0.0f;
        } else {
          u0 = sA[j * 17 + tid];
          const float ej = (j < NN - 1) ? (float)ee[j] : 0.0f;
          u1 = sjm1 ? (-sA[(j - 1) * 17 + tid] * ej) : ej;
          u2 = 0.0f;
        }
        const float yy = (byv[j * 17 + tid] - u1 * y1 - u2 * y2) / u0;
        byv[j * 17 + tid] = yy;
        y2 = y1; y1 = yy;
      }
      double nrm = 0.0;
      for (int i = 0; i < NN; ++i) { const double v = (double)byv[i * 17 + tid]; nrm += v * v; }
      const double inv = 1.0 / sqrt(nrm);
      for (int i = 0; i < NN; ++i) byv[i * 17 + tid] = (float)((double)byv[i * 17 + tid] * inv);
    }
  }
  __syncthreads();

  // ---------------- MGS ----------------
  for (int kk = 1; kk < 16; ++kk) {
    const int j = tid >> 3, s8 = tid & 7;
    double part = 0.0;
    if (j < kk)
      for (int i = s8 * 16; i < s8 * 16 + 16; ++i)
        part += (double)byv[i * 17 + j] * (double)byv[i * 17 + kk];
    for (int off = 4; off > 0; off >>= 1) part += __shfl_down(part, off, 8);
    __syncthreads();
    if (s8 == 0 && j < kk) dred[j] = part;
    __syncthreads();
    if (tid < NN) {
      double acc = (double)byv[tid * 17 + kk];
      for (int j2 = 0; j2 < kk; ++j2) acc -= dred[j2] * (double)byv[tid * 17 + j2];
      byv[tid * 17 + kk] = (float)acc;
    }
    __syncthreads();
    double p2 = 0.0;
    if (tid < NN) { const double v = (double)byv[tid * 17 + kk]; p2 = v * v; }
    const double n2 = blockReduceSum(p2, red, tid);
    if (tid < NN) byv[tid * 17 + kk] = (float)((double)byv[tid * 17 + kk] / sqrt(n2));
    __syncthreads();
  }

  // ---------------- s_k = t . y_k ; pooled ----------------
  if (tid < NN) {
    const int j = tid >> 3, s8 = tid & 7;
    double part = 0.0;
    for (int i = s8 * 16; i < s8 * 16 + 16; ++i)
      part += (double)tvecf[i] * (double)byv[i * 17 + j];
    for (int off = 4; off > 0; off >>= 1) part += __shfl_down(part, off, 8);
    if (s8 == 0) ssv[j] = part;
  }
  __syncthreads();
  if (tid == 0) {
    float lv[16], ev[16];
    float mx = -1e30f;
    for (int i = 0; i < 16; ++i) { lv[i] = (float)lam[i + 1]; mx = fmaxf(mx, -lv[i]); }
    float se = 0.0f;
    for (int i = 0; i < 16; ++i) { ev[i] = expf(-lv[i] - mx); se += ev[i]; }
    for (int i = 0; i < 16; ++i) pool[i] = (ev[i] / se) * (float)ssv[i];
  }
  __syncthreads();

  // ---------------- MLPs + outputs ----------------
  if (tid < NN) {
    float acc = Bb1[tid];
    for (int i = 0; i < 16; ++i) acc = fmaf(pool[i], W1[i * 128 + tid], acc);
    hbuf[tid] = fmaxf(acc, 0.0f);
  }
  __syncthreads();
  if (tid < 64) {
    float acc = Bb2[tid];
    for (int i = 0; i < 128; ++i) acc = fmaf(hbuf[i], W2[i * 64 + tid], acc);
    comb[tid] = acc;                       // spectral
  } else if (tid < NN) {
    comb[tid] = msv[tid - 64];             // ms
  }
  __syncthreads();
  if (tid < NN) {
    float acc = OB1[tid];
    for (int i = 0; i < 128; ++i) acc = fmaf(comb[i], OW1[i * 128 + tid], acc);
    hbuf[tid] = fmaxf(acc, 0.0f);
  }
  __syncthreads();
  if (tid < 16) {
    float acc = OB2[tid];
    for (int i = 0; i < 128; ++i) acc = fmaf(hbuf[i], OW2[i * 16 + tid], acc);
    zrow[tid] = acc;
  }
  __syncthreads();

  const long zeoff = (long)B * 16;
  const long spoff = (long)B * 32;
  const long svoff = (long)B * 32 + (long)B * 64;
  const long coff  = svoff + (long)B * 16;

  if (tid == 0) {
    const float c = 1.0f / (1.0f + expf(-curv[0]));
    float nrm = 0.0f;
    for (int i = 0; i < 16; ++i) nrm += zrow[i] * zrow[i];
    nrm = sqrtf(nrm);
    const float max_r = 0.95f / sqrtf(c);
    sc[3] = (double)fminf(1.0f, max_r / (nrm + 1e-12f));
    if (b == 0) out[coff] = c;
  }
  __syncthreads();
  if (tid < 16) {
    const float fac = (float)sc[3];
    out[b * 16 + tid]          = zrow[tid] * fac;     // z
    out[zeoff + b * 16 + tid]  = zrow[tid];           // z_euclidean
    out[svoff + b * 16 + tid]  = (float)lam[tid + 1]; // sel_vals
  }
  if (tid < 64) out[spoff + b * 64 + tid] = comb[tid]; // spectral
}

extern "C" void kernel_launch(void* const* d_in, const int* in_sizes, int n_in,
                              void* d_out, int out_size, void* d_ws, size_t ws_size,
                              hipStream_t stream) {
  const float* A    = (const float*)d_in[0];
  const float* F    = (const float*)d_in[1];
  const float* swg  = (const float*)d_in[2];
  const float* curv = (const float*)d_in[3];
  const float* W1   = (const float*)d_in[4];
  const float* Bb1  = (const float*)d_in[5];
  const float* W2   = (const float*)d_in[6];
  const float* Bb2  = (const float*)d_in[7];
  const float* OW1  = (const float*)d_in[8];
  const float* OB1  = (const float*)d_in[9];
  const float* OW2  = (const float*)d_in[10];
  const float* OB2  = (const float*)d_in[11];
  float* out = (float*)d_out;
  const int B = in_sizes[0] / (128 * 128);

  holo_kernel<<<dim3(B), dim3(BLK), 0, stream>>>(
      A, F, swg, curv, W1, Bb1, W2, Bb2, OW1, OB1, OW2, OB2, out, B);
}

// Round 17
// 1405.464 us; speedup vs baseline: 1.0949x; 1.0949x over previous
//
#include <hip/hip_runtime.h>
#include <math.h>

#define NN 128
#define BLK 256

__device__ __forceinline__ float hsum4(float4 v) { return (v.x + v.y) + (v.z + v.w); }

__device__ __forceinline__ float bcast(float v, int lane) {
  return __int_as_float(__builtin_amdgcn_readlane(__float_as_int(v), lane));
}

__device__ __forceinline__ float waveRedF(float v) {
#pragma unroll
  for (int off = 32; off > 0; off >>= 1) v += __shfl_down(v, off, 64);
  return v;
}
__device__ __forceinline__ float waveAllRedF(float v) {
#pragma unroll
  for (int off = 32; off > 0; off >>= 1) v += __shfl_xor(v, off, 64);
  return v;
}
__device__ __forceinline__ float getc(float4 a, int c) {
  return (c == 0) ? a.x : (c == 1) ? a.y : (c == 2) ? a.z : a.w;
}
__device__ __forceinline__ float blockReduceSumF(float v, float* redf, int tid) {
  v = waveRedF(v);
  __syncthreads();
  if ((tid & 63) == 0) redf[tid >> 6] = v;
  __syncthreads();
  return (redf[0] + redf[1]) + (redf[2] + redf[3]);
}
__device__ __forceinline__ float startvec(int i, int k) {
  unsigned h = (unsigned)(i * 1664525 + k * 1013904223 + 12345);
  h ^= h >> 13; h *= 2654435761u; h ^= h >> 16;
  return ((float)(h & 0xFFFFFFu) * (1.0f / 16777216.0f)) - 0.5f;
}

extern "C" __global__ void __launch_bounds__(BLK, 4)
holo_kernel(const float* __restrict__ A, const float* __restrict__ F,
            const float* __restrict__ swg, const float* __restrict__ curv,
            const float* __restrict__ W1, const float* __restrict__ Bb1,
            const float* __restrict__ W2, const float* __restrict__ Bb2,
            const float* __restrict__ OW1, const float* __restrict__ OB1,
            const float* __restrict__ OW2, const float* __restrict__ OB2,
            float* __restrict__ out, int B)
{
  __shared__ __align__(16) float wsA[NN * 17];   // pre: scratch arrays; post: byv
  __shared__ __align__(16) float wsB[NN * 17];   // Householder: fscr+corner; invit: sA; MLP
  __shared__ unsigned swb[16 * 5];               // invit pivot bits; bisection: bcnt (uchar)
  __shared__ float  ddf[NN], eef[NN];
  __shared__ float  tvecf[NN];
  __shared__ float  redf[4];
  __shared__ double sc[8];
  __shared__ float  redupf[2], redutf[2], redsigf[2];
  __shared__ float  lamf[20], blof[17], bhif[17];
  __shared__ float  ssvf[16], dredf[16];
  __shared__ float  msv[64], pool[16], zrow[16];

  double* dscr  = (double*)wsA;        // [256] (init only)
  float* svec   = wsA + 512;
  float* invdeg = wsA + 640;
  float* gvv    = wsA + 768;
  float* cw     = wsA + 896;
  float* ubuf   = wsA + 1024;
  float* pbuf   = wsA + 1152;
  float* colk   = wsA + 1280;
  float* byv    = wsA;                 // [128*17] after Householder
  float* fscr   = wsB;                 // [256] during Householder
  float* cornr  = wsB + 256;           // [32*33] corner transfer (after block loop)
  float* sA     = wsB;                 // [128*17] invit LU store
  float* comb   = wsB;                 // [128] MLP
  float* hbuf   = wsB + 128;
  unsigned char* bcnt = (unsigned char*)swb;   // [119] bisection counts (pre-invit)

  const int  tid  = threadIdx.x;
  const int  r    = tid & 127;   // row owned
  const int  h    = tid >> 7;    // column half (cols 64h..64h+63)
  const int  lane = tid & 63;
  const int  widm = tid >> 6;
  const long b    = blockIdx.x;
  const float* Ab = A + b * (long)(NN * NN);
  const float* Fb = F + b * (long)(NN * 64);

  // ---------------- load A: each thread owns half a row in registers ----------------
  float4 areg[16];
  {
    const float4* Arow = reinterpret_cast<const float4*>(Ab + (long)r * NN) + 16 * h;
#pragma unroll
    for (int uu = 0; uu < 16; ++uu) areg[uu] = Arow[uu];
  }
  if (tid == 0) {
    const float a0 = swg[0], a1 = swg[1], a2 = swg[2];
    const float mx = fmaxf(a0, fmaxf(a1, a2));
    const float e0 = expf(a0 - mx), e1 = expf(a1 - mx), e2v = expf(a2 - mx);
    const float s = e0 + e1 + e2v;
    sc[0] = (double)(e0 / s); sc[1] = (double)(e1 / s); sc[2] = (double)(e2v / s);
  }
  // ---------------- degrees ----------------
  {
    float4 s4 = make_float4(0.f, 0.f, 0.f, 0.f);
#pragma unroll
    for (int uu = 0; uu < 16; ++uu) {
      s4.x += areg[uu].x; s4.y += areg[uu].y; s4.z += areg[uu].z; s4.w += areg[uu].w;
    }
    dscr[tid] = (double)hsum4(s4);
  }
  __syncthreads();
  if (tid < NN) {
    const double dg = dscr[tid] + dscr[tid + NN] + 1e-8;
    invdeg[tid] = (float)(1.0 / dg);
    svec[tid]   = (float)(1.0 / sqrt(dg));
  }
  __syncthreads();
  // g = R^T 1
  {
    const float4* iv4 = (const float4*)invdeg;
    float4 acc = make_float4(0.f, 0.f, 0.f, 0.f);
#pragma unroll
    for (int uu = 0; uu < 16; ++uu) {
      const float4 a = areg[uu], w = iv4[16 * h + uu];
      acc.x = fmaf(a.x, w.x, acc.x); acc.y = fmaf(a.y, w.y, acc.y);
      acc.z = fmaf(a.z, w.z, acc.z); acc.w = fmaf(a.w, w.w, acc.w);
    }
    fscr[tid] = hsum4(acc);
  }
  __syncthreads();
  if (tid < NN) {
    const float gv = fscr[tid] + fscr[tid + NN];
    gvv[tid] = gv;
    ubuf[tid] = gv * invdeg[tid];
  }
  __syncthreads();
  // hv = R^T g
  {
    const float4* ub4 = (const float4*)ubuf;
    float4 acc = make_float4(0.f, 0.f, 0.f, 0.f);
#pragma unroll
    for (int uu = 0; uu < 16; ++uu) {
      const float4 a = areg[uu], w = ub4[16 * h + uu];
      acc.x = fmaf(a.x, w.x, acc.x); acc.y = fmaf(a.y, w.y, acc.y);
      acc.z = fmaf(a.z, w.z, acc.z); acc.w = fmaf(a.w, w.w, acc.w);
    }
    fscr[tid] = hsum4(acc);
  }
  __syncthreads();
  if (tid < NN) {
    const float hv = fscr[tid] + fscr[tid + NN];
    cw[tid] = ((float)sc[0] + (float)sc[1] * gvv[tid] + (float)sc[2] * hv) * (1.0f / NN);
  }
  __syncthreads();
  // ms[d] = sum_n cw[n] F[n][d]
  {
    const int d = tid & 63, qt = tid >> 6;
    float acc = 0.0f;
    const float* fb = Fb + qt * 32 * 64;
    for (int n = 0; n < 32; ++n) acc = fmaf(cw[qt * 32 + n], fb[n * 64 + d], acc);
    fscr[tid] = acc;
  }
  __syncthreads();
  if (tid < 64) msv[tid] = (fscr[tid] + fscr[64 + tid]) + (fscr[128 + tid] + fscr[192 + tid]);

  // ---------------- L = I - D^-1/2 A D^-1/2 (registers) ----------------
  {
    const float sr = svec[r];
    const float4* sv4p = (const float4*)svec;
#pragma unroll
    for (int uu = 0; uu < 16; ++uu) {
      const float4 sv = sv4p[16 * h + uu];
      float4 a = areg[uu];
      a.x = -a.x * sr * sv.x; a.y = -a.y * sr * sv.y;
      a.z = -a.z * sr * sv.z; a.w = -a.w * sr * sv.w;
      areg[uu] = a;
    }
    if ((r >> 6) == h) {
      const int cl = r & 63, du = cl >> 2, dc = cl & 3;
#pragma unroll
      for (int uu = 0; uu < 16; ++uu) if (uu == du) {
        float4 a = areg[uu];
        a.x += (dc == 0) ? 1.f : 0.f; a.y += (dc == 1) ? 1.f : 0.f;
        a.z += (dc == 2) ? 1.f : 0.f; a.w += (dc == 3) ? 1.f : 0.f;
        areg[uu] = a;
      }
    }
  }
  // ---------------- prologue: column 0 extract + sigma + tvec init ----------------
  if (tid < NN) tvecf[tid] = 1.0f;
  if (h == 0) {
    const float v0 = areg[0].x;                // column 0
    colk[r] = v0;
    if (r == 0) ddf[0] = v0;
    const float s = waveRedF((r >= 2) ? v0 * v0 : 0.f);
    if (lane == 0) redsigf[widm] = s;
  }
  __syncthreads();

  // ---------------- Householder block phase: k = 0..94 (4 barriers/iter) ----------------
  for (int k = 0; k < 95; ++k) {
    const float sigma  = redsigf[0] + redsigf[1];
    const float alphaf = colk[k + 1];
    float betaf, tauf, sclf;
    if (sigma <= 0.f) { betaf = alphaf; tauf = 0.f; sclf = 0.f; }
    else {
      betaf = (float)(-copysign(sqrt((double)alphaf * (double)alphaf + (double)sigma),
                                (double)alphaf));
      tauf = (betaf - alphaf) / betaf;
      sclf = 1.0f / (alphaf - betaf);
    }
    if (tid == 0) eef[k] = betaf;
    if (h == 0) ubuf[r] = (r <= k) ? 0.f : (r == k + 1) ? 1.f : colk[r] * sclf;
    __syncthreads();                                   // A
    // matvec partials (registers x LDS b128 broadcast u)
    {
      float4 acc = make_float4(0.f, 0.f, 0.f, 0.f);
      if (r >= k + 1 && 64 * h + 63 >= k + 1 && tauf != 0.f) {
        const float4* ub4 = (const float4*)ubuf;
#pragma unroll
        for (int uu = 0; uu < 16; ++uu) {
          if (64 * h + 4 * uu + 3 >= k + 1) {
            const float4 a = areg[uu], u4 = ub4[16 * h + uu];
            acc.x = fmaf(a.x, u4.x, acc.x); acc.y = fmaf(a.y, u4.y, acc.y);
            acc.z = fmaf(a.z, u4.z, acc.z); acc.w = fmaf(a.w, u4.w, acc.w);
          }
        }
      }
      fscr[tid] = hsum4(acc);
    }
    __syncthreads();                                   // B
    if (h == 0) {
      const float p = tauf * (fscr[r] + fscr[r + NN]);
      pbuf[r] = p;
      const float uv = ubuf[r];
      const float s1 = waveRedF(uv * p);
      const float s2 = waveRedF(uv * tvecf[r]);
      if (lane == 0) { redupf[widm] = s1; redutf[widm] = s2; }
    }
    __syncthreads();                                   // C
    {
      const float K   = 0.5f * tauf * (redupf[0] + redupf[1]);
      const float tut = tauf * (redutf[0] + redutf[1]);
      if (r >= k + 1) {
        const float ur = ubuf[r];
        const float qr = fmaf(-K, ur, pbuf[r]);
        if (64 * h + 63 >= k + 1) {
          const float4* ub4 = (const float4*)ubuf;
          const float4* pb4 = (const float4*)pbuf;
#pragma unroll
          for (int uu = 0; uu < 16; ++uu) {
            if (64 * h + 4 * uu + 3 >= k + 1) {
              const float4 u4 = ub4[16 * h + uu], p4 = pb4[16 * h + uu];
              float4 a = areg[uu];
              const float qx = fmaf(-K, u4.x, p4.x);
              const float qy = fmaf(-K, u4.y, p4.y);
              const float qz = fmaf(-K, u4.z, p4.z);
              const float qw = fmaf(-K, u4.w, p4.w);
              a.x -= ur * qx + qr * u4.x;
              a.y -= ur * qy + qr * u4.y;
              a.z -= ur * qz + qr * u4.z;
              a.w -= ur * qw + qr * u4.w;
              areg[uu] = a;
            }
          }
        }
        if (h == 0) tvecf[r] -= tut * ubuf[r];
      }
      const int hstar = (k + 1) >> 6;                  // wave-uniform
      if (h == hstar) {
        float sigp = 0.0f;
        if (r >= k + 1) {
          const int cl = (k + 1) - 64 * hstar, du = cl >> 2, dc = cl & 3;
          float val = 0.f;
#pragma unroll
          for (int uu = 0; uu < 16; ++uu) if (uu == du) val = getc(areg[uu], dc);
          if (r == k + 1) ddf[k + 1] = val;
          else {
            colk[r] = val;
            if (r >= k + 3) sigp = val * val;
          }
        }
        const float s = waveRedF(sigp);
        if (lane == 0) redsigf[widm & 1] = s;
      }
    }
    __syncthreads();                                   // D
  }

  // ---------------- transfer trailing 32x32 (rows/cols 96..127) to LDS ----------------
  if (h == 1 && r >= 96) {                             // tids 224..255
    const int rl = r - 96;
#pragma unroll
    for (int uu = 8; uu < 16; ++uu) {
      const int j0 = (uu - 8) * 4;
      cornr[rl * 33 + j0 + 0] = areg[uu].x;
      cornr[rl * 33 + j0 + 1] = areg[uu].y;
      cornr[rl * 33 + j0 + 2] = areg[uu].z;
      cornr[rl * 33 + j0 + 3] = areg[uu].w;
    }
  }
  __syncthreads();

  // ---------------- wave-synchronous 32x32 corner: k = 95..125 (wave 0, no barriers) ----------------
  if (tid < 64) {
    const bool own = (lane < 32);                      // lane l owns row 96+l
    float arow[32];
#pragma unroll
    for (int j = 0; j < 32; ++j) arow[j] = own ? cornr[lane * 33 + j] : 0.f;
    float colval = own ? colk[96 + lane] : 0.f;        // column 95, rows 96..127
    float tv     = own ? tvecf[96 + lane] : 0.f;

    for (int k = 95; k <= 125; ++k) {
      const int kk = k - 95;
      const float sigp  = (lane >= kk + 1 && lane < 32) ? colval * colval : 0.f;
      const float sigma = waveAllRedF(sigp);
      const float alphaf = bcast(colval, kk);
      float betaf, tauf, sclf;
      if (sigma <= 0.f) { betaf = alphaf; tauf = 0.f; sclf = 0.f; }
      else {
        betaf = -copysignf(sqrtf(fmaf(alphaf, alphaf, sigma)), alphaf);
        tauf = (betaf - alphaf) / betaf;
        sclf = 1.0f / (alphaf - betaf);
      }
      if (lane == 0) eef[k] = betaf;
      const bool live = own && (lane >= kk);
      const float u_me = !live ? 0.f : (lane == kk ? 1.f : colval * sclf);
      float y = 0.f;
#pragma unroll
      for (int j = 0; j < 32; ++j) y = fmaf(arow[j], bcast(u_me, j), y);
      const float p_me = live ? tauf * y : 0.f;
      const float up = waveAllRedF(u_me * p_me);
      const float ut = waveAllRedF(u_me * tv);
      const float K   = 0.5f * tauf * up;
      const float tut = tauf * ut;
      const float q_me = fmaf(-K, u_me, p_me);
      tv -= tut * u_me;
      float ncol = 0.f;
#pragma unroll
      for (int j = 0; j < 32; ++j) {
        const float uj = bcast(u_me, j);
        const float qj = bcast(q_me, j);
        arow[j] -= u_me * qj + q_me * uj;
        if (j == kk) ncol = arow[j];
      }
      if (lane == 0) ddf[k + 1] = bcast(ncol, kk);
      colval = (lane > kk && lane < 32) ? ncol : 0.f;
    }
    const float e126 = bcast(colval, 31);
    const float d127 = bcast(arow[31], 31);
    if (lane == 0) { eef[NN - 2] = e126; ddf[NN - 1] = d127; }
    if (own) tvecf[96 + lane] = tv;
  }
  __syncthreads();

  // ---------------- bisection (multisection x7, 11 rounds; double math, float store) ----------------
  if (tid == 0) {
    double lo = 1e30, hi = -1e30;
    for (int i = 0; i < NN; ++i) {
      const double rr = ((i > 0) ? fabs((double)eef[i - 1]) : 0.0)
                      + ((i < NN - 1) ? fabs((double)eef[i]) : 0.0);
      lo = fmin(lo, (double)ddf[i] - rr);
      hi = fmax(hi, (double)ddf[i] + rr);
    }
    sc[4] = lo - 1e-6; sc[5] = hi + 1e-6;
  }
  __syncthreads();
  if (tid < 17) { blof[tid] = (float)sc[4]; bhif[tid] = (float)sc[5]; }
  __syncthreads();
  for (int round = 0; round < 11; ++round) {
    if (tid < 119) {
      const int ke = tid / 7, j = tid % 7;
      const double lo = (double)blof[ke], hi = (double)bhif[ke];
      const double x = lo + (hi - lo) * ((double)(j + 1) * 0.125);
      int cnt = 0;
      double pm = 1.0, p = (double)ddf[0] - x;
      if (p < 0.0) cnt++;
      for (int i = 1; i < NN; ++i) {
        const double e = (double)eef[i - 1];
        const double pn = ((double)ddf[i] - x) * p - (e * e) * pm;
        pm = p; p = pn;
        if ((p < 0.0) != (pm < 0.0)) cnt++;
        const double ap = fabs(p);
        if (ap > 1e100)                   { p *= 1e-100; pm *= 1e-100; }
        else if (ap < 1e-100 && ap > 0.0) { p *= 1e100;  pm *= 1e100; }
      }
      bcnt[tid] = (unsigned char)cnt;
    }
    __syncthreads();
    if (tid < 17) {
      const float lo = blof[tid], hi = bhif[tid];
      const float w8 = (hi - lo) * 0.125f;
      float nlo = lo, nhi = hi;
      for (int jj = 0; jj < 7; ++jj) {
        const float x = lo + w8 * (float)(jj + 1);
        if ((int)bcnt[tid * 7 + jj] <= tid) nlo = x; else { nhi = x; break; }
      }
      blof[tid] = nlo; bhif[tid] = nhi;
    }
    __syncthreads();
  }
  if (tid < 17) lamf[tid] = 0.5f * (blof[tid] + bhif[tid]);
  __syncthreads();

  // ---------------- inverse iteration on T (lanes 0..15), compressed LU ----------------
  if (tid < 16) {
    const double lk = (double)lamf[tid + 1];
    for (int it = 0; it < 2; ++it) {
      float beta = (float)((double)ddf[0] - lk);
      float gam  = eef[0];
      float rr   = (it == 0) ? startvec(0, tid) : byv[0 * 17 + tid];
      unsigned bw = 0;
      for (int i = 1; i < NN; ++i) {
        const int j = i - 1;
        const float ai = eef[i - 1];
        const float bi = (float)((double)ddf[i] - lk);
        const float ci = (i < NN - 1) ? eef[i] : 0.0f;
        const float ri = (it == 0) ? startvec(i, tid) : byv[i * 17 + tid];
        if (fabsf(beta) >= fabsf(ai)) {
          float piv = (beta == 0.0f) ? 1e-25f : beta;
          const float mm = ai / piv;
          sA [j * 17 + tid] = piv;
          byv[j * 17 + tid] = rr;
          beta = bi - mm * gam;  gam = ci;  rr = ri - mm * rr;
        } else {
          const float mm = beta / ai;
          sA [j * 17 + tid] = mm;
          byv[j * 17 + tid] = ri;
          beta = gam - mm * bi;  gam = -mm * ci;  rr = rr - mm * ri;
          bw |= 1u << (j & 31);
        }
        if ((j & 31) == 31) { swb[tid * 5 + (j >> 5)] = bw; bw = 0; }
      }
      if (beta == 0.0f) beta = 1e-25f;
      sA [127 * 17 + tid] = beta;
      byv[127 * 17 + tid] = rr;
      swb[tid * 5 + 3] = bw;
      float y1 = 0.0f, y2 = 0.0f;
      for (int j = NN - 1; j >= 0; --j) {
        const bool sj = (swb[tid * 5 + (j >> 5)] >> (j & 31)) & 1;
        const bool sjm1 = (j > 0) ? ((swb[tid * 5 + ((j - 1) >> 5)] >> ((j - 1) & 31)) & 1) : false;
        float u0, u1, u2;
        if (sj) {
          u0 = eef[j];
          u1 = (float)((double)ddf[j + 1] - lk);
          u2 = (j < NN - 2) ? eef[j + 1] : 0.0f;
        } else {
          u0 = sA[j * 17 + tid];
          const float ej = (j < NN - 1) ? eef[j] : 0.0f;
          u1 = sjm1 ? (-sA[(j - 1) * 17 + tid] * ej) : ej;
          u2 = 0.0f;
        }
        const float yy = (byv[j * 17 + tid] - u1 * y1 - u2 * y2) / u0;
        byv[j * 17 + tid] = yy;
        y2 = y1; y1 = yy;
      }
      double nrm = 0.0;
      for (int i = 0; i < NN; ++i) { const double v = (double)byv[i * 17 + tid]; nrm += v * v; }
      const double inv = 1.0 / sqrt(nrm);
      for (int i = 0; i < NN; ++i) byv[i * 17 + tid] = (float)((double)byv[i * 17 + tid] * inv);
    }
  }
  __syncthreads();

  // ---------------- MGS (float reductions) ----------------
  for (int kk = 1; kk < 16; ++kk) {
    const int j = tid >> 3, s8 = tid & 7;
    float part = 0.0f;
    if (j < kk)
      for (int i = s8 * 16; i < s8 * 16 + 16; ++i)
        part += byv[i * 17 + j] * byv[i * 17 + kk];
    for (int off = 4; off > 0; off >>= 1) part += __shfl_down(part, off, 8);
    __syncthreads();
    if (s8 == 0 && j < kk) dredf[j] = part;
    __syncthreads();
    if (tid < NN) {
      float acc = byv[tid * 17 + kk];
      for (int j2 = 0; j2 < kk; ++j2) acc -= dredf[j2] * byv[tid * 17 + j2];
      byv[tid * 17 + kk] = acc;
    }
    __syncthreads();
    float p2 = 0.0f;
    if (tid < NN) { const float v = byv[tid * 17 + kk]; p2 = v * v; }
    const float n2 = blockReduceSumF(p2, redf, tid);
    if (tid < NN) byv[tid * 17 + kk] = byv[tid * 17 + kk] / sqrtf(n2);
    __syncthreads();
  }

  // ---------------- s_k = t . y_k ; pooled ----------------
  if (tid < NN) {
    const int j = tid >> 3, s8 = tid & 7;
    float part = 0.0f;
    for (int i = s8 * 16; i < s8 * 16 + 16; ++i)
      part += tvecf[i] * byv[i * 17 + j];
    for (int off = 4; off > 0; off >>= 1) part += __shfl_down(part, off, 8);
    if (s8 == 0) ssvf[j] = part;
  }
  __syncthreads();
  if (tid == 0) {
    float lv[16], ev[16];
    float mx = -1e30f;
    for (int i = 0; i < 16; ++i) { lv[i] = lamf[i + 1]; mx = fmaxf(mx, -lv[i]); }
    float se = 0.0f;
    for (int i = 0; i < 16; ++i) { ev[i] = expf(-lv[i] - mx); se += ev[i]; }
    for (int i = 0; i < 16; ++i) pool[i] = (ev[i] / se) * ssvf[i];
  }
  __syncthreads();

  // ---------------- MLPs + outputs ----------------
  if (tid < NN) {
    float acc = Bb1[tid];
    for (int i = 0; i < 16; ++i) acc = fmaf(pool[i], W1[i * 128 + tid], acc);
    hbuf[tid] = fmaxf(acc, 0.0f);
  }
  __syncthreads();
  if (tid < 64) {
    float acc = Bb2[tid];
    for (int i = 0; i < 128; ++i) acc = fmaf(hbuf[i], W2[i * 64 + tid], acc);
    comb[tid] = acc;                       // spectral
  } else if (tid < NN) {
    comb[tid] = msv[tid - 64];             // ms
  }
  __syncthreads();
  if (tid < NN) {
    float acc = OB1[tid];
    for (int i = 0; i < 128; ++i) acc = fmaf(comb[i], OW1[i * 128 + tid], acc);
    hbuf[tid] = fmaxf(acc, 0.0f);
  }
  __syncthreads();
  if (tid < 16) {
    float acc = OB2[tid];
    for (int i = 0; i < 128; ++i) acc = fmaf(hbuf[i], OW2[i * 16 + tid], acc);
    zrow[tid] = acc;
  }
  __syncthreads();

  const long zeoff = (long)B * 16;
  const long spoff = (long)B * 32;
  const long svoff = (long)B * 32 + (long)B * 64;
  const long coff  = svoff + (long)B * 16;

  if (tid == 0) {
    const float c = 1.0f / (1.0f + expf(-curv[0]));
    float nrm = 0.0f;
    for (int i = 0; i < 16; ++i) nrm += zrow[i] * zrow[i];
    nrm = sqrtf(nrm);
    const float max_r = 0.95f / sqrtf(c);
    sc[3] = (double)fminf(1.0f, max_r / (nrm + 1e-12f));
    if (b == 0) out[coff] = c;
  }
  __syncthreads();
  if (tid < 16) {
    const float fac = (float)sc[3];
    out[b * 16 + tid]          = zrow[tid] * fac;   // z
    out[zeoff + b * 16 + tid]  = zrow[tid];         // z_euclidean
    out[svoff + b * 16 + tid]  = lamf[tid + 1];     // sel_vals
  }
  if (tid < 64) out[spoff + b * 64 + tid] = comb[tid]; // spectral
}

extern "C" void kernel_launch(void* const* d_in, const int* in_sizes, int n_in,
                              void* d_out, int out_size, void* d_ws, size_t ws_size,
                              hipStream_t stream) {
  const float* A    = (const float*)d_in[0];
  const float* F    = (const float*)d_in[1];
  const float* swg  = (const float*)d_in[2];
  const float* curv = (const float*)d_in[3];
  const float* W1   = (const float*)d_in[4];
  const float* Bb1  = (const float*)d_in[5];
  const float* W2   = (const float*)d_in[6];
  const float* Bb2  = (const float*)d_in[7];
  const float* OW1  = (const float*)d_in[8];
  const float* OB1  = (const float*)d_in[9];
  const float* OW2  = (const float*)d_in[10];
  const float* OB2  = (const float*)d_in[11];
  float* out = (float*)d_out;
  const int B = in_sizes[0] / (128 * 128);

  holo_kernel<<<dim3(B), dim3(BLK), 0, stream>>>(
      A, F, swg, curv, W1, Bb1, W2, Bb2, OW1, OB1, OW2, OB2, out, B);
}

// Round 18
// 1396.344 us; speedup vs baseline: 1.1020x; 1.0065x over previous
//
#include <hip/hip_runtime.h>
#include <math.h>

#define NN 128
#define BLK 256
#define CB  88            // corner base: block loop k<87, corner rows/cols 88..127 (40x40)

__device__ __forceinline__ float hsum4(float4 v) { return (v.x + v.y) + (v.z + v.w); }

__device__ __forceinline__ float bcast(float v, int lane) {
  return __int_as_float(__builtin_amdgcn_readlane(__float_as_int(v), lane));
}

__device__ __forceinline__ float waveRedF(float v) {
#pragma unroll
  for (int off = 32; off > 0; off >>= 1) v += __shfl_down(v, off, 64);
  return v;
}
__device__ __forceinline__ float waveAllRedF(float v) {
#pragma unroll
  for (int off = 32; off > 0; off >>= 1) v += __shfl_xor(v, off, 64);
  return v;
}
__device__ __forceinline__ float getc(float4 a, int c) {
  return (c == 0) ? a.x : (c == 1) ? a.y : (c == 2) ? a.z : a.w;
}
__device__ __forceinline__ float startvec(int i, int k) {
  unsigned h = (unsigned)(i * 1664525 + k * 1013904223 + 12345);
  h ^= h >> 13; h *= 2654435761u; h ^= h >> 16;
  return ((float)(h & 0xFFFFFFu) * (1.0f / 16777216.0f)) - 0.5f;
}

extern "C" __global__ void __launch_bounds__(BLK, 4)
holo_kernel(const float* __restrict__ A, const float* __restrict__ F,
            const float* __restrict__ swg, const float* __restrict__ curv,
            const float* __restrict__ W1, const float* __restrict__ Bb1,
            const float* __restrict__ W2, const float* __restrict__ Bb2,
            const float* __restrict__ OW1, const float* __restrict__ OB1,
            const float* __restrict__ OW2, const float* __restrict__ OB2,
            float* __restrict__ out, int B)
{
  __shared__ __align__(16) float wsA[NN * 17];   // pre: scratch arrays; post: byv
  __shared__ __align__(16) float wsB[NN * 17];   // Householder: fscr+corner; invit: sA; MLP
  __shared__ unsigned swb[16 * 5];               // invit pivot bits; bisection: bcnt (uchar)
  __shared__ float  ddf[NN], eef[NN];
  __shared__ float  tvecf[NN];
  __shared__ double sc[8];
  __shared__ float  redupf[2], redutf[2], redsigf[2];
  __shared__ float  lamf[20], blof[17], bhif[17];
  __shared__ float  ssvf[16], dredf[17];
  __shared__ float  msv[64], pool[16], zrow[16];

  double* dscr  = (double*)wsA;        // [256] (init only)
  float* svec   = wsA + 512;
  float* invdeg = wsA + 640;
  float* gvv    = wsA + 768;
  float* cw     = wsA + 896;
  float* ubuf   = wsA + 1024;
  float* pbuf   = wsA + 1152;
  float* colk   = wsA + 1280;
  float* byv    = wsA;                 // [128*17] after Householder
  float* fscr   = wsB;                 // [256] during Householder
  float* cornr  = wsB + 256;           // [40*41] corner transfer (after block loop)
  float* sA     = wsB;                 // [128*17] invit LU store
  float* comb   = wsB;                 // [128] MLP
  float* hbuf   = wsB + 128;
  unsigned char* bcnt = (unsigned char*)swb;   // [119] bisection counts (pre-invit)

  const int  tid  = threadIdx.x;
  const int  r    = tid & 127;   // row owned
  const int  h    = tid >> 7;    // column half (cols 64h..64h+63)
  const int  lane = tid & 63;
  const int  widm = tid >> 6;
  const long b    = blockIdx.x;
  const float* Ab = A + b * (long)(NN * NN);
  const float* Fb = F + b * (long)(NN * 64);

  // ---------------- load A: each thread owns half a row in registers ----------------
  float4 areg[16];
  {
    const float4* Arow = reinterpret_cast<const float4*>(Ab + (long)r * NN) + 16 * h;
#pragma unroll
    for (int uu = 0; uu < 16; ++uu) areg[uu] = Arow[uu];
  }
  if (tid == 0) {
    const float a0 = swg[0], a1 = swg[1], a2 = swg[2];
    const float mx = fmaxf(a0, fmaxf(a1, a2));
    const float e0 = expf(a0 - mx), e1 = expf(a1 - mx), e2v = expf(a2 - mx);
    const float s = e0 + e1 + e2v;
    sc[0] = (double)(e0 / s); sc[1] = (double)(e1 / s); sc[2] = (double)(e2v / s);
  }
  // ---------------- degrees ----------------
  {
    float4 s4 = make_float4(0.f, 0.f, 0.f, 0.f);
#pragma unroll
    for (int uu = 0; uu < 16; ++uu) {
      s4.x += areg[uu].x; s4.y += areg[uu].y; s4.z += areg[uu].z; s4.w += areg[uu].w;
    }
    dscr[tid] = (double)hsum4(s4);
  }
  __syncthreads();
  if (tid < NN) {
    const double dg = dscr[tid] + dscr[tid + NN] + 1e-8;
    invdeg[tid] = (float)(1.0 / dg);
    svec[tid]   = (float)(1.0 / sqrt(dg));
  }
  __syncthreads();
  // g = R^T 1
  {
    const float4* iv4 = (const float4*)invdeg;
    float4 acc = make_float4(0.f, 0.f, 0.f, 0.f);
#pragma unroll
    for (int uu = 0; uu < 16; ++uu) {
      const float4 a = areg[uu], w = iv4[16 * h + uu];
      acc.x = fmaf(a.x, w.x, acc.x); acc.y = fmaf(a.y, w.y, acc.y);
      acc.z = fmaf(a.z, w.z, acc.z); acc.w = fmaf(a.w, w.w, acc.w);
    }
    fscr[tid] = hsum4(acc);
  }
  __syncthreads();
  if (tid < NN) {
    const float gv = fscr[tid] + fscr[tid + NN];
    gvv[tid] = gv;
    ubuf[tid] = gv * invdeg[tid];
  }
  __syncthreads();
  // hv = R^T g
  {
    const float4* ub4 = (const float4*)ubuf;
    float4 acc = make_float4(0.f, 0.f, 0.f, 0.f);
#pragma unroll
    for (int uu = 0; uu < 16; ++uu) {
      const float4 a = areg[uu], w = ub4[16 * h + uu];
      acc.x = fmaf(a.x, w.x, acc.x); acc.y = fmaf(a.y, w.y, acc.y);
      acc.z = fmaf(a.z, w.z, acc.z); acc.w = fmaf(a.w, w.w, acc.w);
    }
    fscr[tid] = hsum4(acc);
  }
  __syncthreads();
  if (tid < NN) {
    const float hv = fscr[tid] + fscr[tid + NN];
    cw[tid] = ((float)sc[0] + (float)sc[1] * gvv[tid] + (float)sc[2] * hv) * (1.0f / NN);
  }
  __syncthreads();
  // ms[d] = sum_n cw[n] F[n][d]
  {
    const int d = tid & 63, qt = tid >> 6;
    float acc = 0.0f;
    const float* fb = Fb + qt * 32 * 64;
    for (int n = 0; n < 32; ++n) acc = fmaf(cw[qt * 32 + n], fb[n * 64 + d], acc);
    fscr[tid] = acc;
  }
  __syncthreads();
  if (tid < 64) msv[tid] = (fscr[tid] + fscr[64 + tid]) + (fscr[128 + tid] + fscr[192 + tid]);

  // ---------------- L = I - D^-1/2 A D^-1/2 (registers) ----------------
  {
    const float sr = svec[r];
    const float4* sv4p = (const float4*)svec;
#pragma unroll
    for (int uu = 0; uu < 16; ++uu) {
      const float4 sv = sv4p[16 * h + uu];
      float4 a = areg[uu];
      a.x = -a.x * sr * sv.x; a.y = -a.y * sr * sv.y;
      a.z = -a.z * sr * sv.z; a.w = -a.w * sr * sv.w;
      areg[uu] = a;
    }
    if ((r >> 6) == h) {
      const int cl = r & 63, du = cl >> 2, dc = cl & 3;
#pragma unroll
      for (int uu = 0; uu < 16; ++uu) if (uu == du) {
        float4 a = areg[uu];
        a.x += (dc == 0) ? 1.f : 0.f; a.y += (dc == 1) ? 1.f : 0.f;
        a.z += (dc == 2) ? 1.f : 0.f; a.w += (dc == 3) ? 1.f : 0.f;
        areg[uu] = a;
      }
    }
  }
  // ---------------- prologue: column 0 extract + sigma + tvec init ----------------
  if (tid < NN) tvecf[tid] = 1.0f;
  if (h == 0) {
    const float v0 = areg[0].x;                // column 0
    colk[r] = v0;
    if (r == 0) ddf[0] = v0;
    const float s = waveRedF((r >= 2) ? v0 * v0 : 0.f);
    if (lane == 0) redsigf[widm] = s;
  }
  __syncthreads();

  // ---------------- Householder block phase: k = 0..86 (4 barriers/iter) ----------------
  for (int k = 0; k < CB - 1; ++k) {
    const float sigma  = redsigf[0] + redsigf[1];
    const float alphaf = colk[k + 1];
    float betaf, tauf, sclf;
    if (sigma <= 0.f) { betaf = alphaf; tauf = 0.f; sclf = 0.f; }
    else {
      betaf = (float)(-copysign(sqrt((double)alphaf * (double)alphaf + (double)sigma),
                                (double)alphaf));
      tauf = (betaf - alphaf) / betaf;
      sclf = 1.0f / (alphaf - betaf);
    }
    if (tid == 0) eef[k] = betaf;
    if (h == 0) ubuf[r] = (r <= k) ? 0.f : (r == k + 1) ? 1.f : colk[r] * sclf;
    __syncthreads();                                   // A
    // matvec partials (registers x LDS b128 broadcast u)
    {
      float4 acc = make_float4(0.f, 0.f, 0.f, 0.f);
      if (r >= k + 1 && 64 * h + 63 >= k + 1 && tauf != 0.f) {
        const float4* ub4 = (const float4*)ubuf;
#pragma unroll
        for (int uu = 0; uu < 16; ++uu) {
          if (64 * h + 4 * uu + 3 >= k + 1) {
            const float4 a = areg[uu], u4 = ub4[16 * h + uu];
            acc.x = fmaf(a.x, u4.x, acc.x); acc.y = fmaf(a.y, u4.y, acc.y);
            acc.z = fmaf(a.z, u4.z, acc.z); acc.w = fmaf(a.w, u4.w, acc.w);
          }
        }
      }
      fscr[tid] = hsum4(acc);
    }
    __syncthreads();                                   // B
    if (h == 0) {
      const float p = tauf * (fscr[r] + fscr[r + NN]);
      pbuf[r] = p;
      const float uv = ubuf[r];
      const float s1 = waveRedF(uv * p);
      const float s2 = waveRedF(uv * tvecf[r]);
      if (lane == 0) { redupf[widm] = s1; redutf[widm] = s2; }
    }
    __syncthreads();                                   // C
    {
      const float K   = 0.5f * tauf * (redupf[0] + redupf[1]);
      const float tut = tauf * (redutf[0] + redutf[1]);
      if (r >= k + 1) {
        const float ur = ubuf[r];
        const float qr = fmaf(-K, ur, pbuf[r]);
        if (64 * h + 63 >= k + 1) {
          const float4* ub4 = (const float4*)ubuf;
          const float4* pb4 = (const float4*)pbuf;
#pragma unroll
          for (int uu = 0; uu < 16; ++uu) {
            if (64 * h + 4 * uu + 3 >= k + 1) {
              const float4 u4 = ub4[16 * h + uu], p4 = pb4[16 * h + uu];
              float4 a = areg[uu];
              const float qx = fmaf(-K, u4.x, p4.x);
              const float qy = fmaf(-K, u4.y, p4.y);
              const float qz = fmaf(-K, u4.z, p4.z);
              const float qw = fmaf(-K, u4.w, p4.w);
              a.x -= ur * qx + qr * u4.x;
              a.y -= ur * qy + qr * u4.y;
              a.z -= ur * qz + qr * u4.z;
              a.w -= ur * qw + qr * u4.w;
              areg[uu] = a;
            }
          }
        }
        if (h == 0) tvecf[r] -= tut * ubuf[r];
      }
      const int hstar = (k + 1) >> 6;                  // wave-uniform
      if (h == hstar) {
        float sigp = 0.0f;
        if (r >= k + 1) {
          const int cl = (k + 1) - 64 * hstar, du = cl >> 2, dc = cl & 3;
          float val = 0.f;
#pragma unroll
          for (int uu = 0; uu < 16; ++uu) if (uu == du) val = getc(areg[uu], dc);
          if (r == k + 1) ddf[k + 1] = val;
          else {
            colk[r] = val;
            if (r >= k + 3) sigp = val * val;
          }
        }
        const float s = waveRedF(sigp);
        if (lane == 0) redsigf[widm & 1] = s;
      }
    }
    __syncthreads();                                   // D
  }

  // ---------------- transfer trailing 40x40 (rows/cols 88..127) to LDS ----------------
  if (h == 1 && r >= CB) {                             // 40 threads
    const int rl = r - CB;
#pragma unroll
    for (int uu = 6; uu < 16; ++uu) {
      const int j0 = (uu - 6) * 4;
      cornr[rl * 41 + j0 + 0] = areg[uu].x;
      cornr[rl * 41 + j0 + 1] = areg[uu].y;
      cornr[rl * 41 + j0 + 2] = areg[uu].z;
      cornr[rl * 41 + j0 + 3] = areg[uu].w;
    }
  }
  __syncthreads();

  // ---------------- wave-synchronous 40x40 corner: k = 87..125 (wave 0, no barriers) ----------------
  if (tid < 64) {
    const bool own = (lane < 40);                      // lane l owns row CB+l
    float arow[40];
#pragma unroll
    for (int j = 0; j < 40; ++j) arow[j] = own ? cornr[lane * 41 + j] : 0.f;
    float colval = own ? colk[CB + lane] : 0.f;        // column CB-1, rows CB..127
    float tv     = own ? tvecf[CB + lane] : 0.f;

    for (int k = CB - 1; k <= 125; ++k) {
      const int kk = k - (CB - 1);
      const float sigp  = (lane >= kk + 1 && lane < 40) ? colval * colval : 0.f;
      const float sigma = waveAllRedF(sigp);
      const float alphaf = bcast(colval, kk);
      float betaf, tauf, sclf;
      if (sigma <= 0.f) { betaf = alphaf; tauf = 0.f; sclf = 0.f; }
      else {
        betaf = -copysignf(sqrtf(fmaf(alphaf, alphaf, sigma)), alphaf);
        tauf = (betaf - alphaf) / betaf;
        sclf = 1.0f / (alphaf - betaf);
      }
      if (lane == 0) eef[k] = betaf;
      const bool live = own && (lane >= kk);
      const float u_me = !live ? 0.f : (lane == kk ? 1.f : colval * sclf);
      float y = 0.f;
#pragma unroll
      for (int j = 0; j < 40; ++j) y = fmaf(arow[j], bcast(u_me, j), y);
      const float p_me = live ? tauf * y : 0.f;
      const float up = waveAllRedF(u_me * p_me);
      const float ut = waveAllRedF(u_me * tv);
      const float K   = 0.5f * tauf * up;
      const float tut = tauf * ut;
      const float q_me = fmaf(-K, u_me, p_me);
      tv -= tut * u_me;
      float ncol = 0.f;
#pragma unroll
      for (int j = 0; j < 40; ++j) {
        const float uj = bcast(u_me, j);
        const float qj = bcast(q_me, j);
        arow[j] -= u_me * qj + q_me * uj;
        if (j == kk) ncol = arow[j];
      }
      if (lane == 0) ddf[k + 1] = bcast(ncol, kk);
      colval = (lane > kk && lane < 40) ? ncol : 0.f;
    }
    const float e126 = bcast(colval, 39);              // column 126, row 127
    const float d127 = bcast(arow[39], 39);            // A[127][127]
    if (lane == 0) { eef[NN - 2] = e126; ddf[NN - 1] = d127; }
    if (own) tvecf[CB + lane] = tv;
  }
  __syncthreads();

  // ---------------- bisection (multisection x7, 11 rounds; double math, float store) ----------------
  if (tid == 0) {
    double lo = 1e30, hi = -1e30;
    for (int i = 0; i < NN; ++i) {
      const double rr = ((i > 0) ? fabs((double)eef[i - 1]) : 0.0)
                      + ((i < NN - 1) ? fabs((double)eef[i]) : 0.0);
      lo = fmin(lo, (double)ddf[i] - rr);
      hi = fmax(hi, (double)ddf[i] + rr);
    }
    sc[4] = lo - 1e-6; sc[5] = hi + 1e-6;
  }
  __syncthreads();
  if (tid < 17) { blof[tid] = (float)sc[4]; bhif[tid] = (float)sc[5]; }
  __syncthreads();
  for (int round = 0; round < 11; ++round) {
    if (tid < 119) {
      const int ke = tid / 7, j = tid % 7;
      const double lo = (double)blof[ke], hi = (double)bhif[ke];
      const double x = lo + (hi - lo) * ((double)(j + 1) * 0.125);
      int cnt = 0;
      double pm = 1.0, p = (double)ddf[0] - x;
      if (p < 0.0) cnt++;
      for (int i = 1; i < NN; ++i) {
        const double e = (double)eef[i - 1];
        const double pn = ((double)ddf[i] - x) * p - (e * e) * pm;
        pm = p; p = pn;
        if ((p < 0.0) != (pm < 0.0)) cnt++;
        const double ap = fabs(p);
        if (ap > 1e100)                   { p *= 1e-100; pm *= 1e-100; }
        else if (ap < 1e-100 && ap > 0.0) { p *= 1e100;  pm *= 1e100; }
      }
      bcnt[tid] = (unsigned char)cnt;
    }
    __syncthreads();
    if (tid < 17) {
      const float lo = blof[tid], hi = bhif[tid];
      const float w8 = (hi - lo) * 0.125f;
      float nlo = lo, nhi = hi;
      for (int jj = 0; jj < 7; ++jj) {
        const float x = lo + w8 * (float)(jj + 1);
        if ((int)bcnt[tid * 7 + jj] <= tid) nlo = x; else { nhi = x; break; }
      }
      blof[tid] = nlo; bhif[tid] = nhi;
    }
    __syncthreads();
  }
  if (tid < 17) lamf[tid] = 0.5f * (blof[tid] + bhif[tid]);
  __syncthreads();

  // ---------------- inverse iteration on T (lanes 0..15), compressed LU ----------------
  if (tid < 16) {
    const double lk = (double)lamf[tid + 1];
    for (int it = 0; it < 2; ++it) {
      float beta = (float)((double)ddf[0] - lk);
      float gam  = eef[0];
      float rr   = (it == 0) ? startvec(0, tid) : byv[0 * 17 + tid];
      unsigned bw = 0;
      for (int i = 1; i < NN; ++i) {
        const int j = i - 1;
        const float ai = eef[i - 1];
        const float bi = (float)((double)ddf[i] - lk);
        const float ci = (i < NN - 1) ? eef[i] : 0.0f;
        const float ri = (it == 0) ? startvec(i, tid) : byv[i * 17 + tid];
        if (fabsf(beta) >= fabsf(ai)) {
          float piv = (beta == 0.0f) ? 1e-25f : beta;
          const float mm = ai / piv;
          sA [j * 17 + tid] = piv;
          byv[j * 17 + tid] = rr;
          beta = bi - mm * gam;  gam = ci;  rr = ri - mm * rr;
        } else {
          const float mm = beta / ai;
          sA [j * 17 + tid] = mm;
          byv[j * 17 + tid] = ri;
          beta = gam - mm * bi;  gam = -mm * ci;  rr = rr - mm * ri;
          bw |= 1u << (j & 31);
        }
        if ((j & 31) == 31) { swb[tid * 5 + (j >> 5)] = bw; bw = 0; }
      }
      if (beta == 0.0f) beta = 1e-25f;
      sA [127 * 17 + tid] = beta;
      byv[127 * 17 + tid] = rr;
      swb[tid * 5 + 3] = bw;
      float y1 = 0.0f, y2 = 0.0f;
      for (int j = NN - 1; j >= 0; --j) {
        const bool sj = (swb[tid * 5 + (j >> 5)] >> (j & 31)) & 1;
        const bool sjm1 = (j > 0) ? ((swb[tid * 5 + ((j - 1) >> 5)] >> ((j - 1) & 31)) & 1) : false;
        float u0, u1, u2;
        if (sj) {
          u0 = eef[j];
          u1 = (float)((double)ddf[j + 1] - lk);
          u2 = (j < NN - 2) ? eef[j + 1] : 0.0f;
        } else {
          u0 = sA[j * 17 + tid];
          const float ej = (j < NN - 1) ? eef[j] : 0.0f;
          u1 = sjm1 ? (-sA[(j - 1) * 17 + tid] * ej) : ej;
          u2 = 0.0f;
        }
        const float yy = (byv[j * 17 + tid] - u1 * y1 - u2 * y2) / u0;
        byv[j * 17 + tid] = yy;
        y2 = y1; y1 = yy;
      }
      double nrm = 0.0;
      for (int i = 0; i < NN; ++i) { const double v = (double)byv[i * 17 + tid]; nrm += v * v; }
      const double inv = 1.0 / sqrt(nrm);
      for (int i = 0; i < NN; ++i) byv[i * 17 + tid] = (float)((double)byv[i * 17 + tid] * inv);
    }
  }
  __syncthreads();

  // ---------------- MGS, 2 barriers/step (projections + self-norm trick) ----------------
  for (int kk = 1; kk < 16; ++kk) {
    const int j = tid >> 3, s8 = tid & 7;
    float part = 0.0f;
    if (tid < NN && j <= kk)
      for (int i = s8 * 16; i < s8 * 16 + 16; ++i)
        part += byv[i * 17 + j] * byv[i * 17 + kk];
    for (int off = 4; off > 0; off >>= 1) part += __shfl_down(part, off, 8);
    if (tid < NN && s8 == 0 && j <= kk) dredf[j] = part;
    __syncthreads();
    if (tid < NN) {
      float acc = byv[tid * 17 + kk];
      float n2  = dredf[kk];                 // ||v||^2 before subtraction
      for (int j2 = 0; j2 < kk; ++j2) {
        const float c = dredf[j2];
        acc -= c * byv[tid * 17 + j2];
        n2  -= c * c;                        // ||v - sum c e||^2 = ||v||^2 - sum c^2
      }
      n2 = fmaxf(n2, 1e-12f);
      byv[tid * 17 + kk] = acc / sqrtf(n2);
    }
    __syncthreads();
  }

  // ---------------- s_k = t . y_k ; pooled ----------------
  if (tid < NN) {
    const int j = tid >> 3, s8 = tid & 7;
    float part = 0.0f;
    for (int i = s8 * 16; i < s8 * 16 + 16; ++i)
      part += tvecf[i] * byv[i * 17 + j];
    for (int off = 4; off > 0; off >>= 1) part += __shfl_down(part, off, 8);
    if (s8 == 0) ssvf[j] = part;
  }
  __syncthreads();
  if (tid == 0) {
    float lv[16], ev[16];
    float mx = -1e30f;
    for (int i = 0; i < 16; ++i) { lv[i] = lamf[i + 1]; mx = fmaxf(mx, -lv[i]); }
    float se = 0.0f;
    for (int i = 0; i < 16; ++i) { ev[i] = expf(-lv[i] - mx); se += ev[i]; }
    for (int i = 0; i < 16; ++i) pool[i] = (ev[i] / se) * ssvf[i];
  }
  __syncthreads();

  // ---------------- MLPs + outputs ----------------
  if (tid < NN) {
    float acc = Bb1[tid];
    for (int i = 0; i < 16; ++i) acc = fmaf(pool[i], W1[i * 128 + tid], acc);
    hbuf[tid] = fmaxf(acc, 0.0f);
  }
  __syncthreads();
  if (tid < 64) {
    float acc = Bb2[tid];
    for (int i = 0; i < 128; ++i) acc = fmaf(hbuf[i], W2[i * 64 + tid], acc);
    comb[tid] = acc;                       // spectral
  } else if (tid < NN) {
    comb[tid] = msv[tid - 64];             // ms
  }
  __syncthreads();
  if (tid < NN) {
    float acc = OB1[tid];
    for (int i = 0; i < 128; ++i) acc = fmaf(comb[i], OW1[i * 128 + tid], acc);
    hbuf[tid] = fmaxf(acc, 0.0f);
  }
  __syncthreads();
  if (tid < 16) {
    float acc = OB2[tid];
    for (int i = 0; i < 128; ++i) acc = fmaf(hbuf[i], OW2[i * 16 + tid], acc);
    zrow[tid] = acc;
  }
  __syncthreads();

  const long zeoff = (long)B * 16;
  const long spoff = (long)B * 32;
  const long svoff = (long)B * 32 + (long)B * 64;
  const long coff  = svoff + (long)B * 16;

  if (tid == 0) {
    const float c = 1.0f / (1.0f + expf(-curv[0]));
    float nrm = 0.0f;
    for (int i = 0; i < 16; ++i) nrm += zrow[i] * zrow[i];
    nrm = sqrtf(nrm);
    const float max_r = 0.95f / sqrtf(c);
    sc[3] = (double)fminf(1.0f, max_r / (nrm + 1e-12f));
    if (b == 0) out[coff] = c;
  }
  __syncthreads();
  if (tid < 16) {
    const float fac = (float)sc[3];
    out[b * 16 + tid]          = zrow[tid] * fac;   // z
    out[zeoff + b * 16 + tid]  = zrow[tid];         // z_euclidean
    out[svoff + b * 16 + tid]  = lamf[tid + 1];     // sel_vals
  }
  if (tid < 64) out[spoff + b * 64 + tid] = comb[tid]; // spectral
}

extern "C" void kernel_launch(void* const* d_in, const int* in_sizes, int n_in,
                              void* d_out, int out_size, void* d_ws, size_t ws_size,
                              hipStream_t stream) {
  const float* A    = (const float*)d_in[0];
  const float* F    = (const float*)d_in[1];
  const float* swg  = (const float*)d_in[2];
  const float* curv = (const float*)d_in[3];
  const float* W1   = (const float*)d_in[4];
  const float* Bb1  = (const float*)d_in[5];
  const float* W2   = (const float*)d_in[6];
  const float* Bb2  = (const float*)d_in[7];
  const float* OW1  = (const float*)d_in[8];
  const float* OB1  = (const float*)d_in[9];
  const float* OW2  = (const float*)d_in[10];
  const float* OB2  = (const float*)d_in[11];
  float* out = (float*)d_out;
  const int B = in_sizes[0] / (128 * 128);

  holo_kernel<<<dim3(B), dim3(BLK), 0, stream>>>(
      A, F, swg, curv, W1, Bb1, W2, Bb2, OW1, OB1, OW2, OB2, out, B);
}

// Round 19
// 1356.724 us; speedup vs baseline: 1.1342x; 1.0292x over previous
//
#include <hip/hip_runtime.h>
#include <math.h>

#define NN 128
#define BLK 256
#define CB  88            // corner base: block loop k<87, corner rows/cols 88..127 (40x40)

__device__ __forceinline__ float hsum4(float4 v) { return (v.x + v.y) + (v.z + v.w); }

__device__ __forceinline__ float bcast(float v, int lane) {
  return __int_as_float(__builtin_amdgcn_readlane(__float_as_int(v), lane));
}

__device__ __forceinline__ float waveRedF(float v) {
#pragma unroll
  for (int off = 32; off > 0; off >>= 1) v += __shfl_down(v, off, 64);
  return v;
}
__device__ __forceinline__ float waveAllRedF(float v) {
#pragma unroll
  for (int off = 32; off > 0; off >>= 1) v += __shfl_xor(v, off, 64);
  return v;
}
__device__ __forceinline__ float getc(float4 a, int c) {
  return (c == 0) ? a.x : (c == 1) ? a.y : (c == 2) ? a.z : a.w;
}
__device__ __forceinline__ float startvec(int i, int k) {
  unsigned h = (unsigned)(i * 1664525 + k * 1013904223 + 12345);
  h ^= h >> 13; h *= 2654435761u; h ^= h >> 16;
  return ((float)(h & 0xFFFFFFu) * (1.0f / 16777216.0f)) - 0.5f;
}

extern "C" __global__ void __launch_bounds__(BLK, 4)
holo_kernel(const float* __restrict__ A, const float* __restrict__ F,
            const float* __restrict__ swg, const float* __restrict__ curv,
            const float* __restrict__ W1, const float* __restrict__ Bb1,
            const float* __restrict__ W2, const float* __restrict__ Bb2,
            const float* __restrict__ OW1, const float* __restrict__ OB1,
            const float* __restrict__ OW2, const float* __restrict__ OB2,
            float* __restrict__ out, int B)
{
  __shared__ __align__(16) float wsA[NN * 17];   // pre: scratch arrays; post: byv
  __shared__ __align__(16) float wsB[NN * 17];   // Householder: fscr+corner; invit: sA; MLP
  __shared__ unsigned swb[16 * 5];               // invit pivot bits; bisection: bcnt (uchar)
  __shared__ float  ddf[NN], eef[NN];
  __shared__ float  tvecf[NN];
  __shared__ double sc[8];
  __shared__ float  redupf[2], redutf[2], redsigf[2];
  __shared__ float  lamf[20], blof[17], bhif[17];
  __shared__ float  ssvf[16], dredf[17];
  __shared__ float  msv[64], pool[16], zrow[16];

  double* dscr  = (double*)wsA;        // [256] (init only)
  float* svec   = wsA + 512;
  float* invdeg = wsA + 640;
  float* gvv    = wsA + 768;
  float* cw     = wsA + 896;
  float* ubuf   = wsA + 1024;
  float* pbuf   = wsA + 1152;
  float* colk   = wsA + 1280;
  float* byv    = wsA;                 // [128*17] after Householder
  float* fscr   = wsB;                 // [256] during Householder
  float* cornr  = wsB + 256;           // [40*41] corner transfer (after block loop)
  float* sA     = wsB;                 // [128*17] invit LU store
  float* comb   = wsB;                 // [128] MLP
  float* hbuf   = wsB + 128;
  unsigned char* bcnt = (unsigned char*)swb;   // [119] bisection counts (pre-invit)

  const int  tid  = threadIdx.x;
  const int  r    = tid & 127;   // row owned
  const int  h    = tid >> 7;    // column half (cols 64h..64h+63)
  const int  lane = tid & 63;
  const int  widm = tid >> 6;
  const long b    = blockIdx.x;
  const float* Ab = A + b * (long)(NN * NN);
  const float* Fb = F + b * (long)(NN * 64);

  // ---------------- load A: each thread owns half a row in registers ----------------
  float4 areg[16];
  {
    const float4* Arow = reinterpret_cast<const float4*>(Ab + (long)r * NN) + 16 * h;
#pragma unroll
    for (int uu = 0; uu < 16; ++uu) areg[uu] = Arow[uu];
  }
  if (tid == 0) {
    const float a0 = swg[0], a1 = swg[1], a2 = swg[2];
    const float mx = fmaxf(a0, fmaxf(a1, a2));
    const float e0 = expf(a0 - mx), e1 = expf(a1 - mx), e2v = expf(a2 - mx);
    const float s = e0 + e1 + e2v;
    sc[0] = (double)(e0 / s); sc[1] = (double)(e1 / s); sc[2] = (double)(e2v / s);
  }
  // ---------------- degrees ----------------
  {
    float4 s4 = make_float4(0.f, 0.f, 0.f, 0.f);
#pragma unroll
    for (int uu = 0; uu < 16; ++uu) {
      s4.x += areg[uu].x; s4.y += areg[uu].y; s4.z += areg[uu].z; s4.w += areg[uu].w;
    }
    dscr[tid] = (double)hsum4(s4);
  }
  __syncthreads();
  if (tid < NN) {
    const double dg = dscr[tid] + dscr[tid + NN] + 1e-8;
    invdeg[tid] = (float)(1.0 / dg);
    svec[tid]   = (float)(1.0 / sqrt(dg));
  }
  __syncthreads();
  // g = R^T 1
  {
    const float4* iv4 = (const float4*)invdeg;
    float4 acc = make_float4(0.f, 0.f, 0.f, 0.f);
#pragma unroll
    for (int uu = 0; uu < 16; ++uu) {
      const float4 a = areg[uu], w = iv4[16 * h + uu];
      acc.x = fmaf(a.x, w.x, acc.x); acc.y = fmaf(a.y, w.y, acc.y);
      acc.z = fmaf(a.z, w.z, acc.z); acc.w = fmaf(a.w, w.w, acc.w);
    }
    fscr[tid] = hsum4(acc);
  }
  __syncthreads();
  if (tid < NN) {
    const float gv = fscr[tid] + fscr[tid + NN];
    gvv[tid] = gv;
    ubuf[tid] = gv * invdeg[tid];
  }
  __syncthreads();
  // hv = R^T g
  {
    const float4* ub4 = (const float4*)ubuf;
    float4 acc = make_float4(0.f, 0.f, 0.f, 0.f);
#pragma unroll
    for (int uu = 0; uu < 16; ++uu) {
      const float4 a = areg[uu], w = ub4[16 * h + uu];
      acc.x = fmaf(a.x, w.x, acc.x); acc.y = fmaf(a.y, w.y, acc.y);
      acc.z = fmaf(a.z, w.z, acc.z); acc.w = fmaf(a.w, w.w, acc.w);
    }
    fscr[tid] = hsum4(acc);
  }
  __syncthreads();
  if (tid < NN) {
    const float hv = fscr[tid] + fscr[tid + NN];
    cw[tid] = ((float)sc[0] + (float)sc[1] * gvv[tid] + (float)sc[2] * hv) * (1.0f / NN);
  }
  __syncthreads();
  // ms[d] = sum_n cw[n] F[n][d]
  {
    const int d = tid & 63, qt = tid >> 6;
    float acc = 0.0f;
    const float* fb = Fb + qt * 32 * 64;
    for (int n = 0; n < 32; ++n) acc = fmaf(cw[qt * 32 + n], fb[n * 64 + d], acc);
    fscr[tid] = acc;
  }
  __syncthreads();
  if (tid < 64) msv[tid] = (fscr[tid] + fscr[64 + tid]) + (fscr[128 + tid] + fscr[192 + tid]);

  // ---------------- L = I - D^-1/2 A D^-1/2 (registers) ----------------
  {
    const float sr = svec[r];
    const float4* sv4p = (const float4*)svec;
#pragma unroll
    for (int uu = 0; uu < 16; ++uu) {
      const float4 sv = sv4p[16 * h + uu];
      float4 a = areg[uu];
      a.x = -a.x * sr * sv.x; a.y = -a.y * sr * sv.y;
      a.z = -a.z * sr * sv.z; a.w = -a.w * sr * sv.w;
      areg[uu] = a;
    }
    if ((r >> 6) == h) {
      const int cl = r & 63, du = cl >> 2, dc = cl & 3;
#pragma unroll
      for (int uu = 0; uu < 16; ++uu) if (uu == du) {
        float4 a = areg[uu];
        a.x += (dc == 0) ? 1.f : 0.f; a.y += (dc == 1) ? 1.f : 0.f;
        a.z += (dc == 2) ? 1.f : 0.f; a.w += (dc == 3) ? 1.f : 0.f;
        areg[uu] = a;
      }
    }
  }
  // ---------------- prologue: column 0 extract + sigma + tvec init ----------------
  if (tid < NN) tvecf[tid] = 1.0f;
  if (h == 0) {
    const float v0 = areg[0].x;                // column 0
    colk[r] = v0;
    if (r == 0) ddf[0] = v0;
    const float s = waveRedF((r >= 2) ? v0 * v0 : 0.f);
    if (lane == 0) redsigf[widm] = s;
  }
  __syncthreads();

  // ---------------- Householder block phase: k = 0..86 (4 barriers/iter) ----------------
  for (int k = 0; k < CB - 1; ++k) {
    const float sigma  = redsigf[0] + redsigf[1];
    const float alphaf = colk[k + 1];
    float betaf, tauf, sclf;
    if (sigma <= 0.f) { betaf = alphaf; tauf = 0.f; sclf = 0.f; }
    else {
      betaf = (float)(-copysign(sqrt((double)alphaf * (double)alphaf + (double)sigma),
                                (double)alphaf));
      tauf = (betaf - alphaf) / betaf;
      sclf = 1.0f / (alphaf - betaf);
    }
    if (tid == 0) eef[k] = betaf;
    if (h == 0) ubuf[r] = (r <= k) ? 0.f : (r == k + 1) ? 1.f : colk[r] * sclf;
    __syncthreads();                                   // A
    // matvec partials (registers x LDS b128 broadcast u)
    {
      float4 acc = make_float4(0.f, 0.f, 0.f, 0.f);
      if (r >= k + 1 && 64 * h + 63 >= k + 1 && tauf != 0.f) {
        const float4* ub4 = (const float4*)ubuf;
#pragma unroll
        for (int uu = 0; uu < 16; ++uu) {
          if (64 * h + 4 * uu + 3 >= k + 1) {
            const float4 a = areg[uu], u4 = ub4[16 * h + uu];
            acc.x = fmaf(a.x, u4.x, acc.x); acc.y = fmaf(a.y, u4.y, acc.y);
            acc.z = fmaf(a.z, u4.z, acc.z); acc.w = fmaf(a.w, u4.w, acc.w);
          }
        }
      }
      fscr[tid] = hsum4(acc);
    }
    __syncthreads();                                   // B
    if (h == 0) {
      const float p = tauf * (fscr[r] + fscr[r + NN]);
      pbuf[r] = p;
      const float uv = ubuf[r];
      const float s1 = waveRedF(uv * p);
      const float s2 = waveRedF(uv * tvecf[r]);
      if (lane == 0) { redupf[widm] = s1; redutf[widm] = s2; }
    }
    __syncthreads();                                   // C
    {
      const float K   = 0.5f * tauf * (redupf[0] + redupf[1]);
      const float tut = tauf * (redutf[0] + redutf[1]);
      if (r >= k + 1) {
        const float ur = ubuf[r];
        const float qr = fmaf(-K, ur, pbuf[r]);
        if (64 * h + 63 >= k + 1) {
          const float4* ub4 = (const float4*)ubuf;
          const float4* pb4 = (const float4*)pbuf;
#pragma unroll
          for (int uu = 0; uu < 16; ++uu) {
            if (64 * h + 4 * uu + 3 >= k + 1) {
              const float4 u4 = ub4[16 * h + uu], p4 = pb4[16 * h + uu];
              float4 a = areg[uu];
              const float qx = fmaf(-K, u4.x, p4.x);
              const float qy = fmaf(-K, u4.y, p4.y);
              const float qz = fmaf(-K, u4.z, p4.z);
              const float qw = fmaf(-K, u4.w, p4.w);
              a.x -= ur * qx + qr * u4.x;
              a.y -= ur * qy + qr * u4.y;
              a.z -= ur * qz + qr * u4.z;
              a.w -= ur * qw + qr * u4.w;
              areg[uu] = a;
            }
          }
        }
        if (h == 0) tvecf[r] -= tut * ubuf[r];
      }
      const int hstar = (k + 1) >> 6;                  // wave-uniform
      if (h == hstar) {
        float sigp = 0.0f;
        if (r >= k + 1) {
          const int cl = (k + 1) - 64 * hstar, du = cl >> 2, dc = cl & 3;
          float val = 0.f;
#pragma unroll
          for (int uu = 0; uu < 16; ++uu) if (uu == du) val = getc(areg[uu], dc);
          if (r == k + 1) ddf[k + 1] = val;
          else {
            colk[r] = val;
            if (r >= k + 3) sigp = val * val;
          }
        }
        const float s = waveRedF(sigp);
        if (lane == 0) redsigf[widm & 1] = s;
      }
    }
    __syncthreads();                                   // D
  }

  // ---------------- transfer trailing 40x40 (rows/cols 88..127) to LDS ----------------
  if (h == 1 && r >= CB) {                             // 40 threads
    const int rl = r - CB;
#pragma unroll
    for (int uu = 6; uu < 16; ++uu) {
      const int j0 = (uu - 6) * 4;
      cornr[rl * 41 + j0 + 0] = areg[uu].x;
      cornr[rl * 41 + j0 + 1] = areg[uu].y;
      cornr[rl * 41 + j0 + 2] = areg[uu].z;
      cornr[rl * 41 + j0 + 3] = areg[uu].w;
    }
  }
  __syncthreads();

  // ---------------- wave-synchronous 40x40 corner: k = 87..125 (wave 0, no barriers) ----------------
  if (tid < 64) {
    __builtin_amdgcn_s_setprio(1);                     // block-critical wave: favor on SIMD
    const bool own = (lane < 40);                      // lane l owns row CB+l
    float arow[40];
#pragma unroll
    for (int j = 0; j < 40; ++j) arow[j] = own ? cornr[lane * 41 + j] : 0.f;
    float colval = own ? colk[CB + lane] : 0.f;        // column CB-1, rows CB..127
    float tv     = own ? tvecf[CB + lane] : 0.f;

    for (int k = CB - 1; k <= 125; ++k) {
      const int kk = k - (CB - 1);
      const float sigp  = (lane >= kk + 1 && lane < 40) ? colval * colval : 0.f;
      const float sigma = waveAllRedF(sigp);
      const float alphaf = bcast(colval, kk);
      float betaf, tauf, sclf;
      if (sigma <= 0.f) { betaf = alphaf; tauf = 0.f; sclf = 0.f; }
      else {
        betaf = -copysignf(sqrtf(fmaf(alphaf, alphaf, sigma)), alphaf);
        tauf = (betaf - alphaf) / betaf;
        sclf = 1.0f / (alphaf - betaf);
      }
      if (lane == 0) eef[k] = betaf;
      const bool live = own && (lane >= kk);
      const float u_me = !live ? 0.f : (lane == kk ? 1.f : colval * sclf);
      float y = 0.f;
#pragma unroll
      for (int j = 0; j < 40; ++j) y = fmaf(arow[j], bcast(u_me, j), y);
      const float p_me = live ? tauf * y : 0.f;
      const float up = waveAllRedF(u_me * p_me);
      const float ut = waveAllRedF(u_me * tv);
      const float K   = 0.5f * tauf * up;
      const float tut = tauf * ut;
      const float q_me = fmaf(-K, u_me, p_me);
      tv -= tut * u_me;
      float ncol = 0.f;
#pragma unroll
      for (int j = 0; j < 40; ++j) {
        const float uj = bcast(u_me, j);
        const float qj = bcast(q_me, j);
        arow[j] -= u_me * qj + q_me * uj;
        if (j == kk) ncol = arow[j];
      }
      const float dnext = bcast(ncol, kk);             // new diagonal (row k+1)
      if (lane == 0) ddf[k + 1] = dnext;
      colval = (lane > kk && lane < 40) ? ncol : 0.f;
    }
    const float e126 = bcast(colval, 39);              // column 126, row 127
    const float d127 = bcast(arow[39], 39);            // A[127][127]
    if (lane == 0) { eef[NN - 2] = e126; ddf[NN - 1] = d127; }
    if (own) tvecf[CB + lane] = tv;
    __builtin_amdgcn_s_setprio(0);
  }
  __syncthreads();

  // ---------------- bisection (multisection x7, 10 rounds; double math, float store) ----------------
  if (tid == 0) {
    double lo = 1e30, hi = -1e30;
    for (int i = 0; i < NN; ++i) {
      const double rr = ((i > 0) ? fabs((double)eef[i - 1]) : 0.0)
                      + ((i < NN - 1) ? fabs((double)eef[i]) : 0.0);
      lo = fmin(lo, (double)ddf[i] - rr);
      hi = fmax(hi, (double)ddf[i] + rr);
    }
    sc[4] = lo - 1e-6; sc[5] = hi + 1e-6;
  }
  __syncthreads();
  if (tid < 17) { blof[tid] = (float)sc[4]; bhif[tid] = (float)sc[5]; }
  __syncthreads();
  for (int round = 0; round < 10; ++round) {
    if (tid < 119) {
      const int ke = tid / 7, j = tid % 7;
      const double lo = (double)blof[ke], hi = (double)bhif[ke];
      const double x = lo + (hi - lo) * ((double)(j + 1) * 0.125);
      int cnt = 0;
      double pm = 1.0, p = (double)ddf[0] - x;
      if (p < 0.0) cnt++;
      for (int i = 1; i < NN; ++i) {
        const double e = (double)eef[i - 1];
        const double pn = ((double)ddf[i] - x) * p - (e * e) * pm;
        pm = p; p = pn;
        if ((p < 0.0) != (pm < 0.0)) cnt++;
        const double ap = fabs(p);
        if (ap > 1e100)                   { p *= 1e-100; pm *= 1e-100; }
        else if (ap < 1e-100 && ap > 0.0) { p *= 1e100;  pm *= 1e100; }
      }
      bcnt[tid] = (unsigned char)cnt;
    }
    __syncthreads();
    if (tid < 17) {
      const float lo = blof[tid], hi = bhif[tid];
      const float w8 = (hi - lo) * 0.125f;
      float nlo = lo, nhi = hi;
      for (int jj = 0; jj < 7; ++jj) {
        const float x = lo + w8 * (float)(jj + 1);
        if ((int)bcnt[tid * 7 + jj] <= tid) nlo = x; else { nhi = x; break; }
      }
      blof[tid] = nlo; bhif[tid] = nhi;
    }
    __syncthreads();
  }
  if (tid < 17) lamf[tid] = 0.5f * (blof[tid] + bhif[tid]);
  __syncthreads();

  // ---------------- inverse iteration on T (lanes 0..15), compressed LU ----------------
  if (tid < 16) {
    const double lk = (double)lamf[tid + 1];
    for (int it = 0; it < 2; ++it) {
      float beta = (float)((double)ddf[0] - lk);
      float gam  = eef[0];
      float rr   = (it == 0) ? startvec(0, tid) : byv[0 * 17 + tid];
      unsigned bw = 0;
      for (int i = 1; i < NN; ++i) {
        const int j = i - 1;
        const float ai = eef[i - 1];
        const float bi = (float)((double)ddf[i] - lk);
        const float ci = (i < NN - 1) ? eef[i] : 0.0f;
        const float ri = (it == 0) ? startvec(i, tid) : byv[i * 17 + tid];
        if (fabsf(beta) >= fabsf(ai)) {
          float piv = (beta == 0.0f) ? 1e-25f : beta;
          const float mm = ai / piv;
          sA [j * 17 + tid] = piv;
          byv[j * 17 + tid] = rr;
          beta = bi - mm * gam;  gam = ci;  rr = ri - mm * rr;
        } else {
          const float mm = beta / ai;
          sA [j * 17 + tid] = mm;
          byv[j * 17 + tid] = ri;
          beta = gam - mm * bi;  gam = -mm * ci;  rr = rr - mm * ri;
          bw |= 1u << (j & 31);
        }
        if ((j & 31) == 31) { swb[tid * 5 + (j >> 5)] = bw; bw = 0; }
      }
      if (beta == 0.0f) beta = 1e-25f;
      sA [127 * 17 + tid] = beta;
      byv[127 * 17 + tid] = rr;
      swb[tid * 5 + 3] = bw;
      float y1 = 0.0f, y2 = 0.0f;
      for (int j = NN - 1; j >= 0; --j) {
        const bool sj = (swb[tid * 5 + (j >> 5)] >> (j & 31)) & 1;
        const bool sjm1 = (j > 0) ? ((swb[tid * 5 + ((j - 1) >> 5)] >> ((j - 1) & 31)) & 1) : false;
        float u0, u1, u2;
        if (sj) {
          u0 = eef[j];
          u1 = (float)((double)ddf[j + 1] - lk);
          u2 = (j < NN - 2) ? eef[j + 1] : 0.0f;
        } else {
          u0 = sA[j * 17 + tid];
          const float ej = (j < NN - 1) ? eef[j] : 0.0f;
          u1 = sjm1 ? (-sA[(j - 1) * 17 + tid] * ej) : ej;
          u2 = 0.0f;
        }
        const float yy = (byv[j * 17 + tid] - u1 * y1 - u2 * y2) / u0;
        byv[j * 17 + tid] = yy;
        y2 = y1; y1 = yy;
      }
      double nrm = 0.0;
      for (int i = 0; i < NN; ++i) { const double v = (double)byv[i * 17 + tid]; nrm += v * v; }
      const double inv = 1.0 / sqrt(nrm);
      for (int i = 0; i < NN; ++i) byv[i * 17 + tid] = (float)((double)byv[i * 17 + tid] * inv);
    }
  }
  __syncthreads();

  // ---------------- MGS, 2 barriers/step (projections + self-norm trick) ----------------
  for (int kk = 1; kk < 16; ++kk) {
    const int j = tid >> 3, s8 = tid & 7;
    float part = 0.0f;
    if (tid < NN && j <= kk)
      for (int i = s8 * 16; i < s8 * 16 + 16; ++i)
        part += byv[i * 17 + j] * byv[i * 17 + kk];
    for (int off = 4; off > 0; off >>= 1) part += __shfl_down(part, off, 8);
    if (tid < NN && s8 == 0 && j <= kk) dredf[j] = part;
    __syncthreads();
    if (tid < NN) {
      float acc = byv[tid * 17 + kk];
      float n2  = dredf[kk];                 // ||v||^2 before subtraction
      for (int j2 = 0; j2 < kk; ++j2) {
        const float c = dredf[j2];
        acc -= c * byv[tid * 17 + j2];
        n2  -= c * c;                        // ||v - sum c e||^2 = ||v||^2 - sum c^2
      }
      n2 = fmaxf(n2, 1e-12f);
      byv[tid * 17 + kk] = acc / sqrtf(n2);
    }
    __syncthreads();
  }

  // ---------------- s_k = t . y_k ; pooled ----------------
  if (tid < NN) {
    const int j = tid >> 3, s8 = tid & 7;
    float part = 0.0f;
    for (int i = s8 * 16; i < s8 * 16 + 16; ++i)
      part += tvecf[i] * byv[i * 17 + j];
    for (int off = 4; off > 0; off >>= 1) part += __shfl_down(part, off, 8);
    if (s8 == 0) ssvf[j] = part;
  }
  __syncthreads();
  if (tid == 0) {
    float lv[16], ev[16];
    float mx = -1e30f;
    for (int i = 0; i < 16; ++i) { lv[i] = lamf[i + 1]; mx = fmaxf(mx, -lv[i]); }
    float se = 0.0f;
    for (int i = 0; i < 16; ++i) { ev[i] = expf(-lv[i] - mx); se += ev[i]; }
    for (int i = 0; i < 16; ++i) pool[i] = (ev[i] / se) * ssvf[i];
  }
  __syncthreads();

  // ---------------- MLPs + outputs ----------------
  if (tid < NN) {
    float acc = Bb1[tid];
    for (int i = 0; i < 16; ++i) acc = fmaf(pool[i], W1[i * 128 + tid], acc);
    hbuf[tid] = fmaxf(acc, 0.0f);
  }
  __syncthreads();
  if (tid < 64) {
    float acc = Bb2[tid];
    for (int i = 0; i < 128; ++i) acc = fmaf(hbuf[i], W2[i * 64 + tid], acc);
    comb[tid] = acc;                       // spectral
  } else if (tid < NN) {
    comb[tid] = msv[tid - 64];             // ms
  }
  __syncthreads();
  if (tid < NN) {
    float acc = OB1[tid];
    for (int i = 0; i < 128; ++i) acc = fmaf(comb[i], OW1[i * 128 + tid], acc);
    hbuf[tid] = fmaxf(acc, 0.0f);
  }
  __syncthreads();
  if (tid < 16) {
    float acc = OB2[tid];
    for (int i = 0; i < 128; ++i) acc = fmaf(hbuf[i], OW2[i * 16 + tid], acc);
    zrow[tid] = acc;
  }
  __syncthreads();

  const long zeoff = (long)B * 16;
  const long spoff = (long)B * 32;
  const long svoff = (long)B * 32 + (long)B * 64;
  const long coff  = svoff + (long)B * 16;

  if (tid == 0) {
    const float c = 1.0f / (1.0f + expf(-curv[0]));
    float nrm = 0.0f;
    for (int i = 0; i < 16; ++i) nrm += zrow[i] * zrow[i];
    nrm = sqrtf(nrm);
    const float max_r = 0.95f / sqrtf(c);
    sc[3] = (double)fminf(1.0f, max_r / (nrm + 1e-12f));
    if (b == 0) out[coff] = c;
  }
  __syncthreads();
  if (tid < 16) {
    const float fac = (float)sc[3];
    out[b * 16 + tid]          = zrow[tid] * fac;   // z
    out[zeoff + b * 16 + tid]  = zrow[tid];         // z_euclidean
    out[svoff + b * 16 + tid]  = lamf[tid + 1];     // sel_vals
  }
  if (tid < 64) out[spoff + b * 64 + tid] = comb[tid]; // spectral
}

extern "C" void kernel_launch(void* const* d_in, const int* in_sizes, int n_in,
                              void* d_out, int out_size, void* d_ws, size_t ws_size,
                              hipStream_t stream) {
  const float* A    = (const float*)d_in[0];
  const float* F    = (const float*)d_in[1];
  const float* swg  = (const float*)d_in[2];
  const float* curv = (const float*)d_in[3];
  const float* W1   = (const float*)d_in[4];
  const float* Bb1  = (const float*)d_in[5];
  const float* W2   = (const float*)d_in[6];
  const float* Bb2  = (const float*)d_in[7];
  const float* OW1  = (const float*)d_in[8];
  const float* OB1  = (const float*)d_in[9];
  const float* OW2  = (const float*)d_in[10];
  const float* OB2  = (const float*)d_in[11];
  float* out = (float*)d_out;
  const int B = in_sizes[0] / (128 * 128);

  holo_kernel<<<dim3(B), dim3(BLK), 0, stream>>>(
      A, F, swg, curv, W1, Bb1, W2, Bb2, OW1, OB1, OW2, OB2, out, B);
}

// Round 20
// 1322.709 us; speedup vs baseline: 1.1634x; 1.0257x over previous
//
#include <hip/hip_runtime.h>
#include <math.h>

#define NN 128
#define BLK 256
#define CB  88            // corner base: block loop k<87, corner rows/cols 88..127 (40x40)

__device__ __forceinline__ float hsum4(float4 v) { return (v.x + v.y) + (v.z + v.w); }

__device__ __forceinline__ float bcast(float v, int lane) {
  return __int_as_float(__builtin_amdgcn_readlane(__float_as_int(v), lane));
}

__device__ __forceinline__ float waveRedF(float v) {
#pragma unroll
  for (int off = 32; off > 0; off >>= 1) v += __shfl_down(v, off, 64);
  return v;
}
__device__ __forceinline__ float waveAllRedF(float v) {
#pragma unroll
  for (int off = 32; off > 0; off >>= 1) v += __shfl_xor(v, off, 64);
  return v;
}
__device__ __forceinline__ float getc(float4 a, int c) {
  return (c == 0) ? a.x : (c == 1) ? a.y : (c == 2) ? a.z : a.w;
}
__device__ __forceinline__ float startvec(int i, int k) {
  unsigned h = (unsigned)(i * 1664525 + k * 1013904223 + 12345);
  h ^= h >> 13; h *= 2654435761u; h ^= h >> 16;
  return ((float)(h & 0xFFFFFFu) * (1.0f / 16777216.0f)) - 0.5f;
}

extern "C" __global__ void __launch_bounds__(BLK, 4)
holo_kernel(const float* __restrict__ A, const float* __restrict__ F,
            const float* __restrict__ swg, const float* __restrict__ curv,
            const float* __restrict__ W1, const float* __restrict__ Bb1,
            const float* __restrict__ W2, const float* __restrict__ Bb2,
            const float* __restrict__ OW1, const float* __restrict__ OB1,
            const float* __restrict__ OW2, const float* __restrict__ OB2,
            float* __restrict__ out, int B)
{
  __shared__ __align__(16) float wsA[NN * 17];   // pre: scratch arrays; post: byv
  __shared__ __align__(16) float wsB[NN * 17];   // Householder: fscr+corner; invit: sA; MLP
  __shared__ unsigned swb[16 * 5];               // invit pivot bits; bisection: bcnt (uchar)
  __shared__ float  ddf[NN], eef[NN];
  __shared__ float  tvecf[NN];
  __shared__ double sc[8];
  __shared__ float  redupf[2], redutf[2], redsigf[2];
  __shared__ float  lamf[20], blof[17], bhif[17];
  __shared__ float  ssvf[16], dredf[17];
  __shared__ float  msv[64], pool[16], zrow[16];

  double* dscr  = (double*)wsA;        // [256] (init only)
  float* svec   = wsA + 512;
  float* invdeg = wsA + 640;
  float* gvv    = wsA + 768;
  float* cw     = wsA + 896;
  float* ubuf   = wsA + 1024;
  float* pbuf   = wsA + 1152;
  float* colk   = wsA + 1280;
  float* byv    = wsA;                 // [128*17] after Householder
  float* fscr   = wsB;                 // [256] during Householder
  float* cornr  = wsB + 256;           // [40*41] corner transfer (after block loop)
  float* sA     = wsB;                 // [128*17] invit LU store
  float* comb   = wsB;                 // [128] MLP
  float* hbuf   = wsB + 128;
  unsigned char* bcnt = (unsigned char*)swb;   // [119] bisection counts (pre-invit)

  const int  tid  = threadIdx.x;
  const int  r    = tid & 127;   // row owned
  const int  h    = tid >> 7;    // column half (cols 64h..64h+63)
  const int  lane = tid & 63;
  const int  widm = tid >> 6;
  const long b    = blockIdx.x;
  const float* Ab = A + b * (long)(NN * NN);
  const float* Fb = F + b * (long)(NN * 64);

  // ---------------- load A: each thread owns half a row in registers ----------------
  float4 areg[16];
  {
    const float4* Arow = reinterpret_cast<const float4*>(Ab + (long)r * NN) + 16 * h;
#pragma unroll
    for (int uu = 0; uu < 16; ++uu) areg[uu] = Arow[uu];
  }
  if (tid == 0) {
    const float a0 = swg[0], a1 = swg[1], a2 = swg[2];
    const float mx = fmaxf(a0, fmaxf(a1, a2));
    const float e0 = expf(a0 - mx), e1 = expf(a1 - mx), e2v = expf(a2 - mx);
    const float s = e0 + e1 + e2v;
    sc[0] = (double)(e0 / s); sc[1] = (double)(e1 / s); sc[2] = (double)(e2v / s);
  }
  // ---------------- degrees ----------------
  {
    float4 s4 = make_float4(0.f, 0.f, 0.f, 0.f);
#pragma unroll
    for (int uu = 0; uu < 16; ++uu) {
      s4.x += areg[uu].x; s4.y += areg[uu].y; s4.z += areg[uu].z; s4.w += areg[uu].w;
    }
    dscr[tid] = (double)hsum4(s4);
  }
  __syncthreads();
  if (tid < NN) {
    const double dg = dscr[tid] + dscr[tid + NN] + 1e-8;
    invdeg[tid] = (float)(1.0 / dg);
    svec[tid]   = (float)(1.0 / sqrt(dg));
  }
  __syncthreads();
  // g = R^T 1
  {
    const float4* iv4 = (const float4*)invdeg;
    float4 acc = make_float4(0.f, 0.f, 0.f, 0.f);
#pragma unroll
    for (int uu = 0; uu < 16; ++uu) {
      const float4 a = areg[uu], w = iv4[16 * h + uu];
      acc.x = fmaf(a.x, w.x, acc.x); acc.y = fmaf(a.y, w.y, acc.y);
      acc.z = fmaf(a.z, w.z, acc.z); acc.w = fmaf(a.w, w.w, acc.w);
    }
    fscr[tid] = hsum4(acc);
  }
  __syncthreads();
  if (tid < NN) {
    const float gv = fscr[tid] + fscr[tid + NN];
    gvv[tid] = gv;
    ubuf[tid] = gv * invdeg[tid];
  }
  __syncthreads();
  // hv = R^T g
  {
    const float4* ub4 = (const float4*)ubuf;
    float4 acc = make_float4(0.f, 0.f, 0.f, 0.f);
#pragma unroll
    for (int uu = 0; uu < 16; ++uu) {
      const float4 a = areg[uu], w = ub4[16 * h + uu];
      acc.x = fmaf(a.x, w.x, acc.x); acc.y = fmaf(a.y, w.y, acc.y);
      acc.z = fmaf(a.z, w.z, acc.z); acc.w = fmaf(a.w, w.w, acc.w);
    }
    fscr[tid] = hsum4(acc);
  }
  __syncthreads();
  if (tid < NN) {
    const float hv = fscr[tid] + fscr[tid + NN];
    cw[tid] = ((float)sc[0] + (float)sc[1] * gvv[tid] + (float)sc[2] * hv) * (1.0f / NN);
  }
  __syncthreads();
  // ms[d] = sum_n cw[n] F[n][d]
  {
    const int d = tid & 63, qt = tid >> 6;
    float acc = 0.0f;
    const float* fb = Fb + qt * 32 * 64;
    for (int n = 0; n < 32; ++n) acc = fmaf(cw[qt * 32 + n], fb[n * 64 + d], acc);
    fscr[tid] = acc;
  }
  __syncthreads();
  if (tid < 64) msv[tid] = (fscr[tid] + fscr[64 + tid]) + (fscr[128 + tid] + fscr[192 + tid]);

  // ---------------- L = I - D^-1/2 A D^-1/2 (registers) ----------------
  {
    const float sr = svec[r];
    const float4* sv4p = (const float4*)svec;
#pragma unroll
    for (int uu = 0; uu < 16; ++uu) {
      const float4 sv = sv4p[16 * h + uu];
      float4 a = areg[uu];
      a.x = -a.x * sr * sv.x; a.y = -a.y * sr * sv.y;
      a.z = -a.z * sr * sv.z; a.w = -a.w * sr * sv.w;
      areg[uu] = a;
    }
    if ((r >> 6) == h) {
      const int cl = r & 63, du = cl >> 2, dc = cl & 3;
#pragma unroll
      for (int uu = 0; uu < 16; ++uu) if (uu == du) {
        float4 a = areg[uu];
        a.x += (dc == 0) ? 1.f : 0.f; a.y += (dc == 1) ? 1.f : 0.f;
        a.z += (dc == 2) ? 1.f : 0.f; a.w += (dc == 3) ? 1.f : 0.f;
        areg[uu] = a;
      }
    }
  }
  // ---------------- prologue: column 0 extract + sigma + tvec init ----------------
  if (tid < NN) tvecf[tid] = 1.0f;
  if (h == 0) {
    const float v0 = areg[0].x;                // column 0
    colk[r] = v0;
    if (r == 0) ddf[0] = v0;
    const float s = waveRedF((r >= 2) ? v0 * v0 : 0.f);
    if (lane == 0) redsigf[widm] = s;
  }
  __syncthreads();

  // ---------------- Householder block phase: k = 0..86 (4 barriers/iter) ----------------
  for (int k = 0; k < CB - 1; ++k) {
    const float sigma  = redsigf[0] + redsigf[1];
    const float alphaf = colk[k + 1];
    float betaf, tauf, sclf;
    if (sigma <= 0.f) { betaf = alphaf; tauf = 0.f; sclf = 0.f; }
    else {
      betaf = (float)(-copysign(sqrt((double)alphaf * (double)alphaf + (double)sigma),
                                (double)alphaf));
      tauf = (betaf - alphaf) / betaf;
      sclf = 1.0f / (alphaf - betaf);
    }
    if (tid == 0) eef[k] = betaf;
    if (h == 0) ubuf[r] = (r <= k) ? 0.f : (r == k + 1) ? 1.f : colk[r] * sclf;
    __syncthreads();                                   // A
    // matvec partials (registers x LDS b128 broadcast u)
    {
      float4 acc = make_float4(0.f, 0.f, 0.f, 0.f);
      if (r >= k + 1 && 64 * h + 63 >= k + 1 && tauf != 0.f) {
        const float4* ub4 = (const float4*)ubuf;
#pragma unroll
        for (int uu = 0; uu < 16; ++uu) {
          if (64 * h + 4 * uu + 3 >= k + 1) {
            const float4 a = areg[uu], u4 = ub4[16 * h + uu];
            acc.x = fmaf(a.x, u4.x, acc.x); acc.y = fmaf(a.y, u4.y, acc.y);
            acc.z = fmaf(a.z, u4.z, acc.z); acc.w = fmaf(a.w, u4.w, acc.w);
          }
        }
      }
      fscr[tid] = hsum4(acc);
    }
    __syncthreads();                                   // B
    if (h == 0) {
      const float p = tauf * (fscr[r] + fscr[r + NN]);
      pbuf[r] = p;
      const float uv = ubuf[r];
      const float s1 = waveRedF(uv * p);
      const float s2 = waveRedF(uv * tvecf[r]);
      if (lane == 0) { redupf[widm] = s1; redutf[widm] = s2; }
    }
    __syncthreads();                                   // C
    {
      const float K   = 0.5f * tauf * (redupf[0] + redupf[1]);
      const float tut = tauf * (redutf[0] + redutf[1]);
      if (r >= k + 1) {
        const float ur = ubuf[r];
        const float qr = fmaf(-K, ur, pbuf[r]);
        if (64 * h + 63 >= k + 1) {
          const float4* ub4 = (const float4*)ubuf;
          const float4* pb4 = (const float4*)pbuf;
#pragma unroll
          for (int uu = 0; uu < 16; ++uu) {
            if (64 * h + 4 * uu + 3 >= k + 1) {
              const float4 u4 = ub4[16 * h + uu], p4 = pb4[16 * h + uu];
              float4 a = areg[uu];
              const float qx = fmaf(-K, u4.x, p4.x);
              const float qy = fmaf(-K, u4.y, p4.y);
              const float qz = fmaf(-K, u4.z, p4.z);
              const float qw = fmaf(-K, u4.w, p4.w);
              a.x -= ur * qx + qr * u4.x;
              a.y -= ur * qy + qr * u4.y;
              a.z -= ur * qz + qr * u4.z;
              a.w -= ur * qw + qr * u4.w;
              areg[uu] = a;
            }
          }
        }
        if (h == 0) tvecf[r] -= tut * ubuf[r];
      }
      const int hstar = (k + 1) >> 6;                  // wave-uniform
      if (h == hstar) {
        float sigp = 0.0f;
        if (r >= k + 1) {
          const int cl = (k + 1) - 64 * hstar, du = cl >> 2, dc = cl & 3;
          float val = 0.f;
#pragma unroll
          for (int uu = 0; uu < 16; ++uu) if (uu == du) val = getc(areg[uu], dc);
          if (r == k + 1) ddf[k + 1] = val;
          else {
            colk[r] = val;
            if (r >= k + 3) sigp = val * val;
          }
        }
        const float s = waveRedF(sigp);
        if (lane == 0) redsigf[widm & 1] = s;
      }
    }
    __syncthreads();                                   // D
  }

  // ---------------- transfer trailing 40x40 (rows/cols 88..127) to LDS ----------------
  if (h == 1 && r >= CB) {                             // 40 threads
    const int rl = r - CB;
#pragma unroll
    for (int uu = 6; uu < 16; ++uu) {
      const int j0 = (uu - 6) * 4;
      cornr[rl * 41 + j0 + 0] = areg[uu].x;
      cornr[rl * 41 + j0 + 1] = areg[uu].y;
      cornr[rl * 41 + j0 + 2] = areg[uu].z;
      cornr[rl * 41 + j0 + 3] = areg[uu].w;
    }
  }
  __syncthreads();

  // ---------------- wave-synchronous 40x40 corner: k = 87..125 (wave 0, no barriers) ----------------
  if (tid < 64) {
    __builtin_amdgcn_s_setprio(1);                     // block-critical wave: favor on SIMD
    const bool own = (lane < 40);                      // lane l owns row CB+l
    float arow[40];
#pragma unroll
    for (int j = 0; j < 40; ++j) arow[j] = own ? cornr[lane * 41 + j] : 0.f;
    float colval = own ? colk[CB + lane] : 0.f;        // column CB-1, rows CB..127
    float tv     = own ? tvecf[CB + lane] : 0.f;

    for (int k = CB - 1; k <= 125; ++k) {
      const int kk = k - (CB - 1);
      const float sigp  = (lane >= kk + 1 && lane < 40) ? colval * colval : 0.f;
      const float sigma = waveAllRedF(sigp);
      const float alphaf = bcast(colval, kk);
      float betaf, tauf, sclf;
      if (sigma <= 0.f) { betaf = alphaf; tauf = 0.f; sclf = 0.f; }
      else {
        betaf = -copysignf(sqrtf(fmaf(alphaf, alphaf, sigma)), alphaf);
        tauf = (betaf - alphaf) / betaf;
        sclf = 1.0f / (alphaf - betaf);
      }
      if (lane == 0) eef[k] = betaf;
      const bool live = own && (lane >= kk);
      const float u_me = !live ? 0.f : (lane == kk ? 1.f : colval * sclf);
      float y = 0.f;
#pragma unroll
      for (int j = 0; j < 40; ++j) y = fmaf(arow[j], bcast(u_me, j), y);
      const float p_me = live ? tauf * y : 0.f;
      const float up = waveAllRedF(u_me * p_me);
      const float ut = waveAllRedF(u_me * tv);
      const float K   = 0.5f * tauf * up;
      const float tut = tauf * ut;
      const float q_me = fmaf(-K, u_me, p_me);
      tv -= tut * u_me;
      float ncol = 0.f;
#pragma unroll
      for (int j = 0; j < 40; ++j) {
        const float uj = bcast(u_me, j);
        const float qj = bcast(q_me, j);
        arow[j] -= u_me * qj + q_me * uj;
        if (j == kk) ncol = arow[j];
      }
      const float dnext = bcast(ncol, kk);             // new diagonal (row k+1)
      if (lane == 0) ddf[k + 1] = dnext;
      colval = (lane > kk && lane < 40) ? ncol : 0.f;
    }
    const float e126 = bcast(colval, 39);              // column 126, row 127
    const float d127 = bcast(arow[39], 39);            // A[127][127]
    if (lane == 0) { eef[NN - 2] = e126; ddf[NN - 1] = d127; }
    if (own) tvecf[CB + lane] = tv;
    __builtin_amdgcn_s_setprio(0);
  }
  __syncthreads();

  // ---------------- bisection (multisection x7, 9 rounds; double math, float store) ----------------
  if (tid == 0) {
    double lo = 1e30, hi = -1e30;
    for (int i = 0; i < NN; ++i) {
      const double rr = ((i > 0) ? fabs((double)eef[i - 1]) : 0.0)
                      + ((i < NN - 1) ? fabs((double)eef[i]) : 0.0);
      lo = fmin(lo, (double)ddf[i] - rr);
      hi = fmax(hi, (double)ddf[i] + rr);
    }
    sc[4] = lo - 1e-6; sc[5] = hi + 1e-6;
  }
  __syncthreads();
  if (tid < 17) { blof[tid] = (float)sc[4]; bhif[tid] = (float)sc[5]; }
  __syncthreads();
  for (int round = 0; round < 9; ++round) {
    if (tid < 119) {
      __builtin_amdgcn_s_setprio(1);                   // serial Sturm chain: favor
      const int ke = tid / 7, j = tid % 7;
      const double lo = (double)blof[ke], hi = (double)bhif[ke];
      const double x = lo + (hi - lo) * ((double)(j + 1) * 0.125);
      int cnt = 0;
      double pm = 1.0, p = (double)ddf[0] - x;
      if (p < 0.0) cnt++;
      for (int i = 1; i < NN; ++i) {
        const double e = (double)eef[i - 1];
        const double pn = ((double)ddf[i] - x) * p - (e * e) * pm;
        pm = p; p = pn;
        if ((p < 0.0) != (pm < 0.0)) cnt++;
        const double ap = fabs(p);
        if (ap > 1e100)                   { p *= 1e-100; pm *= 1e-100; }
        else if (ap < 1e-100 && ap > 0.0) { p *= 1e100;  pm *= 1e100; }
      }
      bcnt[tid] = (unsigned char)cnt;
      __builtin_amdgcn_s_setprio(0);
    }
    __syncthreads();
    if (tid < 17) {
      const float lo = blof[tid], hi = bhif[tid];
      const float w8 = (hi - lo) * 0.125f;
      float nlo = lo, nhi = hi;
      for (int jj = 0; jj < 7; ++jj) {
        const float x = lo + w8 * (float)(jj + 1);
        if ((int)bcnt[tid * 7 + jj] <= tid) nlo = x; else { nhi = x; break; }
      }
      blof[tid] = nlo; bhif[tid] = nhi;
    }
    __syncthreads();
  }
  if (tid < 17) lamf[tid] = 0.5f * (blof[tid] + bhif[tid]);
  __syncthreads();

  // ---------------- inverse iteration on T (lanes 0..15), compressed LU ----------------
  if (tid < 16) {
    __builtin_amdgcn_s_setprio(1);                     // 1-wave serial section: favor
    const double lk = (double)lamf[tid + 1];
    for (int it = 0; it < 2; ++it) {
      float beta = (float)((double)ddf[0] - lk);
      float gam  = eef[0];
      float rr   = (it == 0) ? startvec(0, tid) : byv[0 * 17 + tid];
      unsigned bw = 0;
      for (int i = 1; i < NN; ++i) {
        const int j = i - 1;
        const float ai = eef[i - 1];
        const float bi = (float)((double)ddf[i] - lk);
        const float ci = (i < NN - 1) ? eef[i] : 0.0f;
        const float ri = (it == 0) ? startvec(i, tid) : byv[i * 17 + tid];
        if (fabsf(beta) >= fabsf(ai)) {
          float piv = (beta == 0.0f) ? 1e-25f : beta;
          const float mm = ai / piv;
          sA [j * 17 + tid] = piv;
          byv[j * 17 + tid] = rr;
          beta = bi - mm * gam;  gam = ci;  rr = ri - mm * rr;
        } else {
          const float mm = beta / ai;
          sA [j * 17 + tid] = mm;
          byv[j * 17 + tid] = ri;
          beta = gam - mm * bi;  gam = -mm * ci;  rr = rr - mm * ri;
          bw |= 1u << (j & 31);
        }
        if ((j & 31) == 31) { swb[tid * 5 + (j >> 5)] = bw; bw = 0; }
      }
      if (beta == 0.0f) beta = 1e-25f;
      sA [127 * 17 + tid] = beta;
      byv[127 * 17 + tid] = rr;
      swb[tid * 5 + 3] = bw;
      float y1 = 0.0f, y2 = 0.0f;
      for (int j = NN - 1; j >= 0; --j) {
        const bool sj = (swb[tid * 5 + (j >> 5)] >> (j & 31)) & 1;
        const bool sjm1 = (j > 0) ? ((swb[tid * 5 + ((j - 1) >> 5)] >> ((j - 1) & 31)) & 1) : false;
        float u0, u1, u2;
        if (sj) {
          u0 = eef[j];
          u1 = (float)((double)ddf[j + 1] - lk);
          u2 = (j < NN - 2) ? eef[j + 1] : 0.0f;
        } else {
          u0 = sA[j * 17 + tid];
          const float ej = (j < NN - 1) ? eef[j] : 0.0f;
          u1 = sjm1 ? (-sA[(j - 1) * 17 + tid] * ej) : ej;
          u2 = 0.0f;
        }
        const float yy = (byv[j * 17 + tid] - u1 * y1 - u2 * y2) / u0;
        byv[j * 17 + tid] = yy;
        y2 = y1; y1 = yy;
      }
      double nrm = 0.0;
      for (int i = 0; i < NN; ++i) { const double v = (double)byv[i * 17 + tid]; nrm += v * v; }
      const double inv = 1.0 / sqrt(nrm);
      for (int i = 0; i < NN; ++i) byv[i * 17 + tid] = (float)((double)byv[i * 17 + tid] * inv);
    }
    __builtin_amdgcn_s_setprio(0);
  }
  __syncthreads();

  // ---------------- MGS, 2 barriers/step (projections + self-norm trick) ----------------
  for (int kk = 1; kk < 16; ++kk) {
    const int j = tid >> 3, s8 = tid & 7;
    float part = 0.0f;
    if (tid < NN && j <= kk)
      for (int i = s8 * 16; i < s8 * 16 + 16; ++i)
        part += byv[i * 17 + j] * byv[i * 17 + kk];
    for (int off = 4; off > 0; off >>= 1) part += __shfl_down(part, off, 8);
    if (tid < NN && s8 == 0 && j <= kk) dredf[j] = part;
    __syncthreads();
    if (tid < NN) {
      float acc = byv[tid * 17 + kk];
      float n2  = dredf[kk];                 // ||v||^2 before subtraction
      for (int j2 = 0; j2 < kk; ++j2) {
        const float c = dredf[j2];
        acc -= c * byv[tid * 17 + j2];
        n2  -= c * c;                        // ||v - sum c e||^2 = ||v||^2 - sum c^2
      }
      n2 = fmaxf(n2, 1e-12f);
      byv[tid * 17 + kk] = acc / sqrtf(n2);
    }
    __syncthreads();
  }

  // ---------------- s_k = t . y_k ; pooled ----------------
  if (tid < NN) {
    const int j = tid >> 3, s8 = tid & 7;
    float part = 0.0f;
    for (int i = s8 * 16; i < s8 * 16 + 16; ++i)
      part += tvecf[i] * byv[i * 17 + j];
    for (int off = 4; off > 0; off >>= 1) part += __shfl_down(part, off, 8);
    if (s8 == 0) ssvf[j] = part;
  }
  __syncthreads();
  if (tid == 0) {
    float lv[16], ev[16];
    float mx = -1e30f;
    for (int i = 0; i < 16; ++i) { lv[i] = lamf[i + 1]; mx = fmaxf(mx, -lv[i]); }
    float se = 0.0f;
    for (int i = 0; i < 16; ++i) { ev[i] = expf(-lv[i] - mx); se += ev[i]; }
    for (int i = 0; i < 16; ++i) pool[i] = (ev[i] / se) * ssvf[i];
  }
  __syncthreads();

  // ---------------- MLPs + outputs ----------------
  if (tid < NN) {
    float acc = Bb1[tid];
    for (int i = 0; i < 16; ++i) acc = fmaf(pool[i], W1[i * 128 + tid], acc);
    hbuf[tid] = fmaxf(acc, 0.0f);
  }
  __syncthreads();
  if (tid < 64) {
    float acc = Bb2[tid];
    for (int i = 0; i < 128; ++i) acc = fmaf(hbuf[i], W2[i * 64 + tid], acc);
    comb[tid] = acc;                       // spectral
  } else if (tid < NN) {
    comb[tid] = msv[tid - 64];             // ms
  }
  __syncthreads();
  if (tid < NN) {
    float acc = OB1[tid];
    for (int i = 0; i < 128; ++i) acc = fmaf(comb[i], OW1[i * 128 + tid], acc);
    hbuf[tid] = fmaxf(acc, 0.0f);
  }
  __syncthreads();
  if (tid < 16) {
    float acc = OB2[tid];
    for (int i = 0; i < 128; ++i) acc = fmaf(hbuf[i], OW2[i * 16 + tid], acc);
    zrow[tid] = acc;
  }
  __syncthreads();

  const long zeoff = (long)B * 16;
  const long spoff = (long)B * 32;
  const long svoff = (long)B * 32 + (long)B * 64;
  const long coff  = svoff + (long)B * 16;

  if (tid == 0) {
    const float c = 1.0f / (1.0f + expf(-curv[0]));
    float nrm = 0.0f;
    for (int i = 0; i < 16; ++i) nrm += zrow[i] * zrow[i];
    nrm = sqrtf(nrm);
    const float max_r = 0.95f / sqrtf(c);
    sc[3] = (double)fminf(1.0f, max_r / (nrm + 1e-12f));
    if (b == 0) out[coff] = c;
  }
  __syncthreads();
  if (tid < 16) {
    const float fac = (float)sc[3];
    out[b * 16 + tid]          = zrow[tid] * fac;   // z
    out[zeoff + b * 16 + tid]  = zrow[tid];         // z_euclidean
    out[svoff + b * 16 + tid]  = lamf[tid + 1];     // sel_vals
  }
  if (tid < 64) out[spoff + b * 64 + tid] = comb[tid]; // spectral
}

extern "C" void kernel_launch(void* const* d_in, const int* in_sizes, int n_in,
                              void* d_out, int out_size, void* d_ws, size_t ws_size,
                              hipStream_t stream) {
  const float* A    = (const float*)d_in[0];
  const float* F    = (const float*)d_in[1];
  const float* swg  = (const float*)d_in[2];
  const float* curv = (const float*)d_in[3];
  const float* W1   = (const float*)d_in[4];
  const float* Bb1  = (const float*)d_in[5];
  const float* W2   = (const float*)d_in[6];
  const float* Bb2  = (const float*)d_in[7];
  const float* OW1  = (const float*)d_in[8];
  const float* OB1  = (const float*)d_in[9];
  const float* OW2  = (const float*)d_in[10];
  const float* OB2  = (const float*)d_in[11];
  float* out = (float*)d_out;
  const int B = in_sizes[0] / (128 * 128);

  holo_kernel<<<dim3(B), dim3(BLK), 0, stream>>>(
      A, F, swg, curv, W1, Bb1, W2, Bb2, OW1, OB1, OW2, OB2, out, B);
}